// Round 1
// baseline (1148.507 us; speedup 1.0000x reference)
//
#include <hip/hip_runtime.h>
#include <cmath>

// B=8, N=512, V=8000, H=256
// Pipeline:
//   k_transpose_bf16: emb_w (8000x256 f32) -> embT (256x8000 bf16); wh -> whT (256x256 bf16)
//   k_embed_gemm:     partials[kc][4096][256] = inputs @ emb_w   (bf16 MFMA, K split x5)
//   k_reduce_wx:      xw[4096][256] = (sum_kc partials + emb_b) @ wx + hb   (fp32)
//   k_rnn_scan:       512 sequential steps, single block, wh in registers as MFMA B-frags
//   k_logits_softmax: softmax(hT @ out_w + out_b)  (fp32)

typedef float f32x4 __attribute__((ext_vector_type(4)));
typedef __bf16 bf16x8 __attribute__((ext_vector_type(8)));

#define BM 64
#define BN 256
#define BK 64
#define KSPLIT 5
#define KCH 1600   // 8000 / KSPLIT, = 25 * BK
#define NITER 25

// ---------------- transpose + f32->bf16 (64x64 tiles) ----------------
__global__ __launch_bounds__(256) void k_transpose_bf16(const float* __restrict__ in,
                                                        __bf16* __restrict__ out,
                                                        int R, int C) {
  __shared__ __bf16 lt[64][72];  // +8 pad
  const int tid = threadIdx.x;
  const int r0 = blockIdx.x * 64, c0 = blockIdx.y * 64;
  {
    const int rr = tid >> 2, cg = (tid & 3) * 16;
    const float* src = &in[(size_t)(r0 + rr) * C + c0 + cg];
#pragma unroll
    for (int u = 0; u < 16; u += 4) {
      f32x4 v = *(const f32x4*)(src + u);
      lt[rr][cg + u + 0] = (__bf16)v[0];
      lt[rr][cg + u + 1] = (__bf16)v[1];
      lt[rr][cg + u + 2] = (__bf16)v[2];
      lt[rr][cg + u + 3] = (__bf16)v[3];
    }
  }
  __syncthreads();
  {
    const int cc = tid >> 2, rg = (tid & 3) * 16;
    bf16x8 o0, o1;
#pragma unroll
    for (int e = 0; e < 8; ++e) o0[e] = lt[rg + e][cc];
#pragma unroll
    for (int e = 0; e < 8; ++e) o1[e] = lt[rg + 8 + e][cc];
    __bf16* dst = &out[(size_t)(c0 + cc) * R + r0 + rg];
    *(bf16x8*)(dst) = o0;
    *(bf16x8*)(dst + 8) = o1;
  }
}

// ---------------- embedding GEMM: partials[kc] = inputs @ emb_w ----------------
// A = inputs (4096 x 8000) f32 row-major, staged -> bf16
// B = embT   (256 x 8000)  bf16 [n][k]
// grid (64 M-blocks, KSPLIT), 512 threads = 8 waves (2M x 4N), wave tile 32x64
__global__ __launch_bounds__(512) void k_embed_gemm(const float* __restrict__ inp,
                                                    const __bf16* __restrict__ embT,
                                                    float* __restrict__ part) {
  __shared__ __bf16 sA[BM * BK];  // [row][k], elem idx ^ ((row&7)<<3)
  __shared__ __bf16 sB[BN * BK];  // [col][k], elem idx ^ ((col&7)<<3)
  const int tid = threadIdx.x;
  const int m0 = blockIdx.x * BM;
  const int kc = blockIdx.y;
  const size_t kbase0 = (size_t)kc * KCH;
  const int lane = tid & 63;
  const int w = tid >> 6;
  const int wm = w >> 2, wn = w & 3;
  const int l16 = lane & 15, lk = lane >> 4;

  // staging maps
  const int ar = tid >> 3, ac = (tid & 7) * 8;   // A: 64 rows, 8 thr/row x 8 cols
  const int bc = tid >> 1, bk = (tid & 1) * 32;  // B: 256 cols, 2 thr/col x 32 k

  f32x4 acc[2][4] = {};

  // prologue loads (it = 0)
  const float* aptr = &inp[(size_t)(m0 + ar) * 8000 + kbase0 + ac];
  const __bf16* bptr = &embT[(size_t)bc * 8000 + kbase0 + bk];
  f32x4 a0 = *(const f32x4*)(aptr);
  f32x4 a1 = *(const f32x4*)(aptr + 4);
  bf16x8 b0 = *(const bf16x8*)(bptr);
  bf16x8 b1 = *(const bf16x8*)(bptr + 8);
  bf16x8 b2 = *(const bf16x8*)(bptr + 16);
  bf16x8 b3 = *(const bf16x8*)(bptr + 24);

  const int aswz = (ar & 7) << 3;
  const int bswz = (bc & 7) << 3;

  for (int it = 0; it < NITER; ++it) {
    __syncthreads();  // prior iter's LDS reads done
    // convert + write LDS
    bf16x8 aw;
    aw[0] = (__bf16)a0[0]; aw[1] = (__bf16)a0[1]; aw[2] = (__bf16)a0[2]; aw[3] = (__bf16)a0[3];
    aw[4] = (__bf16)a1[0]; aw[5] = (__bf16)a1[1]; aw[6] = (__bf16)a1[2]; aw[7] = (__bf16)a1[3];
    *(bf16x8*)&sA[(ar * BK + ac) ^ aswz] = aw;
    *(bf16x8*)&sB[(bc * BK + bk + 0) ^ bswz] = b0;
    *(bf16x8*)&sB[(bc * BK + bk + 8) ^ bswz] = b1;
    *(bf16x8*)&sB[(bc * BK + bk + 16) ^ bswz] = b2;
    *(bf16x8*)&sB[(bc * BK + bk + 24) ^ bswz] = b3;
    __syncthreads();

    // issue next-iter global loads (overlap with MFMA)
    if (it + 1 < NITER) {
      const float* ap = aptr + (size_t)(it + 1) * BK;
      const __bf16* bp = bptr + (size_t)(it + 1) * BK;
      a0 = *(const f32x4*)(ap);
      a1 = *(const f32x4*)(ap + 4);
      b0 = *(const bf16x8*)(bp);
      b1 = *(const bf16x8*)(bp + 8);
      b2 = *(const bf16x8*)(bp + 16);
      b3 = *(const bf16x8*)(bp + 24);
    }

    // compute
#pragma unroll
    for (int s = 0; s < 2; ++s) {
      bf16x8 af[2], bfb[4];
#pragma unroll
      for (int i = 0; i < 2; ++i) {
        const int r = wm * 32 + i * 16 + l16;
        af[i] = *(const bf16x8*)&sA[(r * BK + s * 32 + lk * 8) ^ ((r & 7) << 3)];
      }
#pragma unroll
      for (int j = 0; j < 4; ++j) {
        const int c = wn * 64 + j * 16 + l16;
        bfb[j] = *(const bf16x8*)&sB[(c * BK + s * 32 + lk * 8) ^ ((c & 7) << 3)];
      }
#pragma unroll
      for (int i = 0; i < 2; ++i)
#pragma unroll
        for (int j = 0; j < 4; ++j)
          acc[i][j] = __builtin_amdgcn_mfma_f32_16x16x32_bf16(af[i], bfb[j], acc[i][j], 0, 0, 0);
    }
  }

  // epilogue: store partials
#pragma unroll
  for (int i = 0; i < 2; ++i)
#pragma unroll
    for (int j = 0; j < 4; ++j) {
#pragma unroll
      for (int e = 0; e < 4; ++e) {
        const int gr = m0 + wm * 32 + i * 16 + lk * 4 + e;
        const int gc = wn * 64 + j * 16 + l16;
        part[((size_t)kc * 4096 + gr) * 256 + gc] = acc[i][j][e];
      }
    }
}

// ---------------- reduce partials + emb_b, then @wx + hb -> xw ----------------
__global__ __launch_bounds__(256) void k_reduce_wx(const float* __restrict__ part,
                                                   const float* __restrict__ emb_b,
                                                   const float* __restrict__ wx,
                                                   const float* __restrict__ hb,
                                                   float* __restrict__ xw) {
  __shared__ float xs[256];
  const int m = blockIdx.x;
  const int h = threadIdx.x;
  float s = emb_b[h];
#pragma unroll
  for (int c = 0; c < KSPLIT; ++c) s += part[((size_t)c * 4096 + m) * 256 + h];
  xs[h] = s;
  __syncthreads();
  float acc = hb[h];
#pragma unroll 4
  for (int k = 0; k < 256; ++k) acc += xs[k] * wx[k * 256 + h];
  xw[(size_t)m * 256 + h] = acc;
}

// ---------------- sequential RNN scan: h = tanh(h @ wh + xw[t]) ----------------
// single block, 1024 threads = 16 waves; wave w owns output cols [w*16, w*16+16)
// wh held in registers as MFMA B-fragments (from whT); h in swizzled LDS (16x256, rows 8..15 = 0)
__global__ __launch_bounds__(1024) void k_rnn_scan(const __bf16* __restrict__ whT,
                                                   const float* __restrict__ xw,
                                                   float* __restrict__ hT) {
  __shared__ __bf16 hA[16 * 256];
  const int tid = threadIdx.x;
  const int lane = tid & 63;
  const int w = tid >> 6;  // 0..15
  const int l16 = lane & 15, lk = lane >> 4;
  const int col = w * 16 + l16;

  // load wh B-fragments: whB[s] lane holds wh[k = s*32 + lk*8 + e][col]
  bf16x8 whB[8];
#pragma unroll
  for (int s = 0; s < 8; ++s)
    whB[s] = *(const bf16x8*)&whT[(size_t)col * 256 + s * 32 + lk * 8];

  // zero h (rows 8..15 stay zero forever)
  for (int i = tid; i < 16 * 256; i += 1024) hA[i] = (__bf16)0.0f;

  const bool act = (lk < 2);  // lanes owning valid output rows (b = lk*4+e < 8)
  float xv[4];
#pragma unroll
  for (int e = 0; e < 4; ++e) {
    const int b = lk * 4 + e;
    xv[e] = act ? xw[((size_t)b * 512 + 0) * 256 + col] : 0.0f;
  }
  __syncthreads();

  for (int t = 0; t < 512; ++t) {
    // read A-fragments of h (broadcast across waves)
    bf16x8 af[8];
#pragma unroll
    for (int s = 0; s < 8; ++s) {
      const int r = l16;
      af[s] = *(const bf16x8*)&hA[(r * 256 + s * 32 + lk * 8) ^ ((r & 7) << 3)];
    }
    __syncthreads();  // all reads done before any write (syncthreads drains lgkm)

    f32x4 acc = {};
#pragma unroll
    for (int s = 0; s < 8; ++s)
      acc = __builtin_amdgcn_mfma_f32_16x16x32_bf16(af[s], whB[s], acc, 0, 0, 0);

    // prefetch next step's xw while MFMA chain drains
    const int tn = (t + 1 < 512) ? t + 1 : 511;
    float xn[4];
#pragma unroll
    for (int e = 0; e < 4; ++e) {
      const int b = lk * 4 + e;
      xn[e] = act ? xw[((size_t)b * 512 + tn) * 256 + col] : 0.0f;
    }

    if (act) {
#pragma unroll
      for (int e = 0; e < 4; ++e) {
        const float v = acc[e] + xv[e];
        const float ex = __expf(2.0f * v);
        const float hn = 1.0f - 2.0f / (ex + 1.0f);  // tanh(v), stable at +-inf
        const int b = lk * 4 + e;
        hA[(b * 256 + col) ^ ((b & 7) << 3)] = (__bf16)hn;
        if (t == 511) hT[b * 256 + col] = hn;
      }
    }
    __syncthreads();  // writes visible before next step's reads
#pragma unroll
    for (int e = 0; e < 4; ++e) xv[e] = xn[e];
  }
}

// ---------------- logits + softmax (fp32) ----------------
// one block per batch b; thread covers 8 consecutive v (8000 = 1000 threads x 8)
__global__ __launch_bounds__(1024) void k_logits_softmax(const float* __restrict__ hT,
                                                         const float* __restrict__ out_w,
                                                         const float* __restrict__ out_b,
                                                         float* __restrict__ out) {
  __shared__ float hs[256];
  __shared__ float red[16];
  const int b = blockIdx.x;
  const int tid = threadIdx.x;
  if (tid < 256) hs[tid] = hT[b * 256 + tid];
  __syncthreads();

  const bool active = tid < 1000;
  const int v0 = tid * 8;
  f32x4 acc0 = {}, acc1 = {};
  if (active) {
#pragma unroll 4
    for (int k = 0; k < 256; ++k) {
      const float hv = hs[k];
      const float* wr = &out_w[(size_t)k * 8000 + v0];
      acc0 += hv * (*(const f32x4*)(wr));
      acc1 += hv * (*(const f32x4*)(wr + 4));
    }
    acc0 += *(const f32x4*)&out_b[v0];
    acc1 += *(const f32x4*)&out_b[v0 + 4];
  }

  // block max
  float m = -__builtin_huge_valf();
  if (active) {
#pragma unroll
    for (int e = 0; e < 4; ++e) m = fmaxf(m, fmaxf(acc0[e], acc1[e]));
  }
#pragma unroll
  for (int off = 32; off > 0; off >>= 1) m = fmaxf(m, __shfl_xor(m, off));
  if ((tid & 63) == 0) red[tid >> 6] = m;
  __syncthreads();
  if (tid < 64) {
    float t = (tid < 16) ? red[tid] : -__builtin_huge_valf();
#pragma unroll
    for (int off = 8; off > 0; off >>= 1) t = fmaxf(t, __shfl_xor(t, off));
    if (tid == 0) red[0] = t;
  }
  __syncthreads();
  const float M = red[0];

  // exp + block sum
  f32x4 e0 = {}, e1 = {};
  float s = 0.0f;
  if (active) {
#pragma unroll
    for (int e = 0; e < 4; ++e) {
      e0[e] = __expf(acc0[e] - M);
      e1[e] = __expf(acc1[e] - M);
      s += e0[e] + e1[e];
    }
  }
#pragma unroll
  for (int off = 32; off > 0; off >>= 1) s += __shfl_xor(s, off);
  if ((tid & 63) == 0) red[tid >> 6] = s;
  __syncthreads();
  if (tid < 64) {
    float t = (tid < 16) ? red[tid] : 0.0f;
#pragma unroll
    for (int off = 8; off > 0; off >>= 1) t += __shfl_xor(t, off);
    if (tid == 0) red[0] = t;
  }
  __syncthreads();
  const float inv = 1.0f / red[0];

  if (active) {
    float* op = &out[(size_t)b * 8000 + v0];
    *(f32x4*)(op) = e0 * inv;
    *(f32x4*)(op + 4) = e1 * inv;
  }
}

// ---------------- launch ----------------
extern "C" void kernel_launch(void* const* d_in, const int* in_sizes, int n_in,
                              void* d_out, int out_size, void* d_ws, size_t ws_size,
                              hipStream_t stream) {
  const float* inputs = (const float*)d_in[0];  // (8,512,8000)
  const float* emb_w  = (const float*)d_in[1];  // (8000,256)
  const float* emb_b  = (const float*)d_in[2];  // (256)
  const float* wx     = (const float*)d_in[3];  // (256,256)
  const float* wh     = (const float*)d_in[4];  // (256,256)
  const float* hb     = (const float*)d_in[5];  // (1,256)
  const float* out_w  = (const float*)d_in[6];  // (256,8000)
  const float* out_b  = (const float*)d_in[7];  // (8000)
  float* out = (float*)d_out;                   // (8,1,8000)

  char* ws = (char*)d_ws;
  __bf16* embT = (__bf16*)(ws + 0);              // 256x8000 bf16 = 4,096,000 B
  __bf16* whT  = (__bf16*)(ws + 4096000);        // 256x256 bf16  =   131,072 B
  float* part  = (float*)(ws + 4227072);         // 5x4096x256 f32 = 20,971,520 B
  float* xw    = (float*)(ws + 25198592);        // 4096x256 f32  =  4,194,304 B
  float* hT    = (float*)(ws + 29392896);        // 8x256 f32     =      8,192 B
  // total ws use: ~29.4 MB

  k_transpose_bf16<<<dim3(125, 4), 256, 0, stream>>>(emb_w, embT, 8000, 256);
  k_transpose_bf16<<<dim3(4, 4), 256, 0, stream>>>(wh, whT, 256, 256);
  k_embed_gemm<<<dim3(64, KSPLIT), 512, 0, stream>>>(inputs, embT, part);
  k_reduce_wx<<<4096, 256, 0, stream>>>(part, emb_b, wx, hb, xw);
  k_rnn_scan<<<1, 1024, 0, stream>>>(whT, xw, hT);
  k_logits_softmax<<<8, 1024, 0, stream>>>(hT, out_w, out_b, out);
}

// Round 2
// 964.824 us; speedup vs baseline: 1.1904x; 1.1904x over previous
//
#include <hip/hip_runtime.h>
#include <cmath>

// B=8, N=512, V=8000, H=256
// Pipeline:
//   k_transpose_bf16: emb_w (8000x256 f32) -> embT (256x8000 bf16); wh -> whT (256x256 bf16)
//   k_embed_gemm:     partials[kc][4096][256] = inputs @ emb_w   (bf16 MFMA, K split x5)
//   k_reduce_wx:      xw3[t][h][b] = ((sum_kc partials + emb_b) @ wx + hb)   (fp32, 8 rows/block)
//   k_rnn_scan:       512 sequential steps, 1 block x 8 waves, raw-barrier pipeline,
//                     xw staged via global_load_lds ring (counted vmcnt), h double-buffered LDS
//   k_logits_softmax: softmax(hT @ out_w + out_b)  (fp32)

typedef float f32x4 __attribute__((ext_vector_type(4)));
typedef __bf16 bf16x8 __attribute__((ext_vector_type(8)));

typedef const __attribute__((address_space(1))) void g_void;
typedef __attribute__((address_space(3))) void l_void;

#define BM 64
#define BN 256
#define BK 64
#define KSPLIT 5
#define KCH 1600   // 8000 / KSPLIT, = 25 * BK
#define NITER 25

// ---------------- transpose + f32->bf16 (64x64 tiles) ----------------
__global__ __launch_bounds__(256) void k_transpose_bf16(const float* __restrict__ in,
                                                        __bf16* __restrict__ out,
                                                        int R, int C) {
  __shared__ __bf16 lt[64][72];  // +8 pad
  const int tid = threadIdx.x;
  const int r0 = blockIdx.x * 64, c0 = blockIdx.y * 64;
  {
    const int rr = tid >> 2, cg = (tid & 3) * 16;
    const float* src = &in[(size_t)(r0 + rr) * C + c0 + cg];
#pragma unroll
    for (int u = 0; u < 16; u += 4) {
      f32x4 v = *(const f32x4*)(src + u);
      lt[rr][cg + u + 0] = (__bf16)v[0];
      lt[rr][cg + u + 1] = (__bf16)v[1];
      lt[rr][cg + u + 2] = (__bf16)v[2];
      lt[rr][cg + u + 3] = (__bf16)v[3];
    }
  }
  __syncthreads();
  {
    const int cc = tid >> 2, rg = (tid & 3) * 16;
    bf16x8 o0, o1;
#pragma unroll
    for (int e = 0; e < 8; ++e) o0[e] = lt[rg + e][cc];
#pragma unroll
    for (int e = 0; e < 8; ++e) o1[e] = lt[rg + 8 + e][cc];
    __bf16* dst = &out[(size_t)(c0 + cc) * R + r0 + rg];
    *(bf16x8*)(dst) = o0;
    *(bf16x8*)(dst + 8) = o1;
  }
}

// ---------------- embedding GEMM: partials[kc] = inputs @ emb_w ----------------
__global__ __launch_bounds__(512) void k_embed_gemm(const float* __restrict__ inp,
                                                    const __bf16* __restrict__ embT,
                                                    float* __restrict__ part) {
  __shared__ __bf16 sA[BM * BK];  // [row][k], elem idx ^ ((row&7)<<3)
  __shared__ __bf16 sB[BN * BK];  // [col][k], elem idx ^ ((col&7)<<3)
  const int tid = threadIdx.x;
  const int m0 = blockIdx.x * BM;
  const int kc = blockIdx.y;
  const size_t kbase0 = (size_t)kc * KCH;
  const int lane = tid & 63;
  const int w = tid >> 6;
  const int wm = w >> 2, wn = w & 3;
  const int l16 = lane & 15, lk = lane >> 4;

  const int ar = tid >> 3, ac = (tid & 7) * 8;   // A: 64 rows, 8 thr/row x 8 cols
  const int bc = tid >> 1, bk = (tid & 1) * 32;  // B: 256 cols, 2 thr/col x 32 k

  f32x4 acc[2][4] = {};

  const float* aptr = &inp[(size_t)(m0 + ar) * 8000 + kbase0 + ac];
  const __bf16* bptr = &embT[(size_t)bc * 8000 + kbase0 + bk];
  f32x4 a0 = *(const f32x4*)(aptr);
  f32x4 a1 = *(const f32x4*)(aptr + 4);
  bf16x8 b0 = *(const bf16x8*)(bptr);
  bf16x8 b1 = *(const bf16x8*)(bptr + 8);
  bf16x8 b2 = *(const bf16x8*)(bptr + 16);
  bf16x8 b3 = *(const bf16x8*)(bptr + 24);

  const int aswz = (ar & 7) << 3;
  const int bswz = (bc & 7) << 3;

  for (int it = 0; it < NITER; ++it) {
    __syncthreads();
    bf16x8 aw;
    aw[0] = (__bf16)a0[0]; aw[1] = (__bf16)a0[1]; aw[2] = (__bf16)a0[2]; aw[3] = (__bf16)a0[3];
    aw[4] = (__bf16)a1[0]; aw[5] = (__bf16)a1[1]; aw[6] = (__bf16)a1[2]; aw[7] = (__bf16)a1[3];
    *(bf16x8*)&sA[(ar * BK + ac) ^ aswz] = aw;
    *(bf16x8*)&sB[(bc * BK + bk + 0) ^ bswz] = b0;
    *(bf16x8*)&sB[(bc * BK + bk + 8) ^ bswz] = b1;
    *(bf16x8*)&sB[(bc * BK + bk + 16) ^ bswz] = b2;
    *(bf16x8*)&sB[(bc * BK + bk + 24) ^ bswz] = b3;
    __syncthreads();

    if (it + 1 < NITER) {
      const float* ap = aptr + (size_t)(it + 1) * BK;
      const __bf16* bp = bptr + (size_t)(it + 1) * BK;
      a0 = *(const f32x4*)(ap);
      a1 = *(const f32x4*)(ap + 4);
      b0 = *(const bf16x8*)(bp);
      b1 = *(const bf16x8*)(bp + 8);
      b2 = *(const bf16x8*)(bp + 16);
      b3 = *(const bf16x8*)(bp + 24);
    }

#pragma unroll
    for (int s = 0; s < 2; ++s) {
      bf16x8 af[2], bfb[4];
#pragma unroll
      for (int i = 0; i < 2; ++i) {
        const int r = wm * 32 + i * 16 + l16;
        af[i] = *(const bf16x8*)&sA[(r * BK + s * 32 + lk * 8) ^ ((r & 7) << 3)];
      }
#pragma unroll
      for (int j = 0; j < 4; ++j) {
        const int c = wn * 64 + j * 16 + l16;
        bfb[j] = *(const bf16x8*)&sB[(c * BK + s * 32 + lk * 8) ^ ((c & 7) << 3)];
      }
#pragma unroll
      for (int i = 0; i < 2; ++i)
#pragma unroll
        for (int j = 0; j < 4; ++j)
          acc[i][j] = __builtin_amdgcn_mfma_f32_16x16x32_bf16(af[i], bfb[j], acc[i][j], 0, 0, 0);
    }
  }

#pragma unroll
  for (int i = 0; i < 2; ++i)
#pragma unroll
    for (int j = 0; j < 4; ++j) {
#pragma unroll
      for (int e = 0; e < 4; ++e) {
        const int gr = m0 + wm * 32 + i * 16 + lk * 4 + e;
        const int gc = wn * 64 + j * 16 + l16;
        part[((size_t)kc * 4096 + gr) * 256 + gc] = acc[i][j][e];
      }
    }
}

// ---------------- reduce partials + emb_b, then @wx + hb -> xw3[t][h][b] ----------------
#define RW_MT 8
__global__ __launch_bounds__(256) void k_reduce_wx(const float* __restrict__ part,
                                                   const float* __restrict__ emb_b,
                                                   const float* __restrict__ wx,
                                                   const float* __restrict__ hb,
                                                   float* __restrict__ xw3) {
  __shared__ float xs[RW_MT][256];
  const int m0 = blockIdx.x * RW_MT;
  const int h = threadIdx.x;
  const float eb = emb_b[h];
#pragma unroll
  for (int mi = 0; mi < RW_MT; ++mi) {
    float s = eb;
#pragma unroll
    for (int c = 0; c < KSPLIT; ++c) s += part[((size_t)c * 4096 + m0 + mi) * 256 + h];
    xs[mi][h] = s;
  }
  __syncthreads();
  float acc[RW_MT];
  const float hbv = hb[h];
#pragma unroll
  for (int mi = 0; mi < RW_MT; ++mi) acc[mi] = hbv;
  for (int k = 0; k < 256; k += 4) {
    const float w0 = wx[(k + 0) * 256 + h];
    const float w1 = wx[(k + 1) * 256 + h];
    const float w2 = wx[(k + 2) * 256 + h];
    const float w3 = wx[(k + 3) * 256 + h];
#pragma unroll
    for (int mi = 0; mi < RW_MT; ++mi) {
      f32x4 xv = *(const f32x4*)&xs[mi][k];
      acc[mi] += xv[0] * w0 + xv[1] * w1 + xv[2] * w2 + xv[3] * w3;
    }
  }
#pragma unroll
  for (int mi = 0; mi < RW_MT; ++mi) {
    const int m = m0 + mi;
    const int b = m >> 9, t = m & 511;
    xw3[((size_t)t * 256 + h) * 8 + b] = acc[mi];  // [t][h][b]
  }
}

// ---------------- sequential RNN scan ----------------
// 1 block x 512 threads (8 waves); wave w owns cols [w*32, w*32+32) (2 col-tiles)
// wh as static B-frags in regs; h double-buffered in LDS (8x256 bf16, XOR-swizzled);
// xw staged 8 steps/chunk into a 2-buffer LDS ring via global_load_lds (counted vmcnt);
// one raw s_barrier per step with manual lgkmcnt(0).
__device__ __forceinline__ void gload_lds16(const float* g, float* l) {
  __builtin_amdgcn_global_load_lds((g_void*)g, (l_void*)l, 16, 0, 0);
}

__global__ __launch_bounds__(512) void k_rnn_scan(const __bf16* __restrict__ whT,
                                                  const float* __restrict__ xw3,
                                                  float* __restrict__ hT) {
  __shared__ __bf16 hA[2][8 * 256];     // 8 KB  (h, batch-major rows 0..7)
  __shared__ float ring[2][8 * 2048];   // 128 KB (8 steps x [h][b] per buffer)
  const int tid = threadIdx.x;
  const int lane = tid & 63;
  const int w = tid >> 6;               // 0..7
  const int l16 = lane & 15, lk = lane >> 4;
  const bool rdact = (l16 < 8);         // lanes holding valid (nonzero) A rows
  const bool wract = (lk < 2);          // lanes owning valid output batches
  const int b4 = lk * 4;

  // static B fragments: wh[k][col] for 2 col-tiles
  bf16x8 whB[2][8];
#pragma unroll
  for (int j = 0; j < 2; ++j) {
    const int col = w * 32 + j * 16 + l16;
#pragma unroll
    for (int s = 0; s < 8; ++s)
      whB[j][s] = *(const bf16x8*)&whT[(size_t)col * 256 + s * 32 + lk * 8];
  }

  // zero h buffer 0
  for (int i = tid; i < 8 * 256; i += 512) hA[0][i] = (__bf16)0.0f;

  // stage chunk 0 into ring[0]
  {
    const float* src = xw3 + (size_t)w * 2048 + lane * 4;
#pragma unroll
    for (int i = 0; i < 8; ++i)
      gload_lds16(src + i * 256, &ring[0][w * 2048 + i * 256]);
  }
  asm volatile("s_waitcnt vmcnt(0)" ::: "memory");
  __syncthreads();

  bf16x8 af[8];
#pragma unroll
  for (int s = 0; s < 8; ++s) af[s] = bf16x8{};

  for (int t = 0; t < 512; ++t) {
    const int cur = t & 1;
    const int rb = (t >> 3) & 1;

    // ---- read phase: A-frags of h (masked to valid rows) + this step's xw
    if (rdact) {
#pragma unroll
      for (int s = 0; s < 8; ++s)
        af[s] = *(const bf16x8*)&hA[cur][(l16 * 256 + s * 32 + lk * 8) ^ (l16 << 3)];
    }
    f32x4 xv[2];
#pragma unroll
    for (int j = 0; j < 2; ++j) {
      xv[j] = f32x4{};
      if (wract) {
        const int col = w * 32 + j * 16 + l16;
        xv[j] = *(const f32x4*)&ring[rb][(t & 7) * 2048 + col * 8 + b4];
      }
    }

    // ---- issue next-chunk staging (completes ~7 steps later; never drained hot)
    if ((t & 7) == 0 && t + 8 < 512) {
      const int c1 = (t >> 3) + 1;
      const int nb = c1 & 1;
      const float* src = xw3 + (size_t)c1 * 16384 + w * 2048 + lane * 4;
#pragma unroll
      for (int i = 0; i < 8; ++i)
        gload_lds16(src + i * 256, &ring[nb][w * 2048 + i * 256]);
    }

    // ---- compute: 2 col-tiles, K split into 4 partial accumulators (chain depth 2)
    f32x4 o[2];
#pragma unroll
    for (int j = 0; j < 2; ++j) {
      f32x4 p0 = {}, p1 = {}, p2 = {}, p3 = {};
      p0 = __builtin_amdgcn_mfma_f32_16x16x32_bf16(af[0], whB[j][0], p0, 0, 0, 0);
      p1 = __builtin_amdgcn_mfma_f32_16x16x32_bf16(af[1], whB[j][1], p1, 0, 0, 0);
      p2 = __builtin_amdgcn_mfma_f32_16x16x32_bf16(af[2], whB[j][2], p2, 0, 0, 0);
      p3 = __builtin_amdgcn_mfma_f32_16x16x32_bf16(af[3], whB[j][3], p3, 0, 0, 0);
      p0 = __builtin_amdgcn_mfma_f32_16x16x32_bf16(af[4], whB[j][4], p0, 0, 0, 0);
      p1 = __builtin_amdgcn_mfma_f32_16x16x32_bf16(af[5], whB[j][5], p1, 0, 0, 0);
      p2 = __builtin_amdgcn_mfma_f32_16x16x32_bf16(af[6], whB[j][6], p2, 0, 0, 0);
      p3 = __builtin_amdgcn_mfma_f32_16x16x32_bf16(af[7], whB[j][7], p3, 0, 0, 0);
      o[j] = (p0 + p1) + (p2 + p3) + xv[j];
    }

    // ---- tanh + write new h to the other buffer
    if (wract) {
#pragma unroll
      for (int j = 0; j < 2; ++j) {
        const int col = w * 32 + j * 16 + l16;
#pragma unroll
        for (int e = 0; e < 4; ++e) {
          const float v = o[j][e];
          const float ex = __expf(2.0f * v);
          const float hn = 1.0f - 2.0f / (ex + 1.0f);  // tanh(v)
          const int b = b4 + e;
          hA[cur ^ 1][(b * 256 + col) ^ (b << 3)] = (__bf16)hn;
          if (t == 511) hT[b * 256 + col] = hn;
        }
      }
    }

    // ---- chunk boundary: ensure next ring buffer is filled (loads issued 7 steps ago)
    if ((t & 7) == 7) asm volatile("s_waitcnt vmcnt(0)" ::: "memory");
    // ---- single barrier per step: my ds_writes committed, then sync
    asm volatile("s_waitcnt lgkmcnt(0)" ::: "memory");
    __builtin_amdgcn_sched_barrier(0);
    __builtin_amdgcn_s_barrier();
    __builtin_amdgcn_sched_barrier(0);
  }
}

// ---------------- logits + softmax (fp32) ----------------
__global__ __launch_bounds__(1024) void k_logits_softmax(const float* __restrict__ hT,
                                                         const float* __restrict__ out_w,
                                                         const float* __restrict__ out_b,
                                                         float* __restrict__ out) {
  __shared__ float hs[256];
  __shared__ float red[16];
  const int b = blockIdx.x;
  const int tid = threadIdx.x;
  if (tid < 256) hs[tid] = hT[b * 256 + tid];
  __syncthreads();

  const bool active = tid < 1000;
  const int v0 = tid * 8;
  f32x4 acc0 = {}, acc1 = {};
  if (active) {
#pragma unroll 4
    for (int k = 0; k < 256; ++k) {
      const float hv = hs[k];
      const float* wr = &out_w[(size_t)k * 8000 + v0];
      acc0 += hv * (*(const f32x4*)(wr));
      acc1 += hv * (*(const f32x4*)(wr + 4));
    }
    acc0 += *(const f32x4*)&out_b[v0];
    acc1 += *(const f32x4*)&out_b[v0 + 4];
  }

  float m = -__builtin_huge_valf();
  if (active) {
#pragma unroll
    for (int e = 0; e < 4; ++e) m = fmaxf(m, fmaxf(acc0[e], acc1[e]));
  }
#pragma unroll
  for (int off = 32; off > 0; off >>= 1) m = fmaxf(m, __shfl_xor(m, off));
  if ((tid & 63) == 0) red[tid >> 6] = m;
  __syncthreads();
  if (tid < 64) {
    float t = (tid < 16) ? red[tid] : -__builtin_huge_valf();
#pragma unroll
    for (int off = 8; off > 0; off >>= 1) t = fmaxf(t, __shfl_xor(t, off));
    if (tid == 0) red[0] = t;
  }
  __syncthreads();
  const float M = red[0];

  f32x4 e0 = {}, e1 = {};
  float s = 0.0f;
  if (active) {
#pragma unroll
    for (int e = 0; e < 4; ++e) {
      e0[e] = __expf(acc0[e] - M);
      e1[e] = __expf(acc1[e] - M);
      s += e0[e] + e1[e];
    }
  }
#pragma unroll
  for (int off = 32; off > 0; off >>= 1) s += __shfl_xor(s, off);
  if ((tid & 63) == 0) red[tid >> 6] = s;
  __syncthreads();
  if (tid < 64) {
    float t = (tid < 16) ? red[tid] : 0.0f;
#pragma unroll
    for (int off = 8; off > 0; off >>= 1) t += __shfl_xor(t, off);
    if (tid == 0) red[0] = t;
  }
  __syncthreads();
  const float inv = 1.0f / red[0];

  if (active) {
    float* op = &out[(size_t)b * 8000 + v0];
    *(f32x4*)(op) = e0 * inv;
    *(f32x4*)(op + 4) = e1 * inv;
  }
}

// ---------------- launch ----------------
extern "C" void kernel_launch(void* const* d_in, const int* in_sizes, int n_in,
                              void* d_out, int out_size, void* d_ws, size_t ws_size,
                              hipStream_t stream) {
  const float* inputs = (const float*)d_in[0];  // (8,512,8000)
  const float* emb_w  = (const float*)d_in[1];  // (8000,256)
  const float* emb_b  = (const float*)d_in[2];  // (256)
  const float* wx     = (const float*)d_in[3];  // (256,256)
  const float* wh     = (const float*)d_in[4];  // (256,256)
  const float* hb     = (const float*)d_in[5];  // (1,256)
  const float* out_w  = (const float*)d_in[6];  // (256,8000)
  const float* out_b  = (const float*)d_in[7];  // (8000)
  float* out = (float*)d_out;                   // (8,1,8000)

  char* ws = (char*)d_ws;
  __bf16* embT = (__bf16*)(ws + 0);              // 256x8000 bf16 = 4,096,000 B
  __bf16* whT  = (__bf16*)(ws + 4096000);        // 256x256 bf16  =   131,072 B
  float* part  = (float*)(ws + 4227072);         // 5x4096x256 f32 = 20,971,520 B
  float* xw3   = (float*)(ws + 25198592);        // [512][256][8] f32 = 4,194,304 B
  float* hT    = (float*)(ws + 29392896);        // 8x256 f32     =      8,192 B

  k_transpose_bf16<<<dim3(125, 4), 256, 0, stream>>>(emb_w, embT, 8000, 256);
  k_transpose_bf16<<<dim3(4, 4), 256, 0, stream>>>(wh, whT, 256, 256);
  k_embed_gemm<<<dim3(64, KSPLIT), 512, 0, stream>>>(inputs, embT, part);
  k_reduce_wx<<<512, 256, 0, stream>>>(part, emb_b, wx, hb, xw3);
  k_rnn_scan<<<1, 512, 0, stream>>>(whT, xw3, hT);
  k_logits_softmax<<<8, 1024, 0, stream>>>(hT, out_w, out_b, out);
}

// Round 4
// 693.332 us; speedup vs baseline: 1.6565x; 1.3916x over previous
//
#include <hip/hip_runtime.h>
#include <cmath>

// B=8, N=512, V=8000, H=256
// Pipeline:
//   k_transpose_bf16: emb_w (8000x256 f32) -> embT (256x8000 bf16); wh -> whT
//   k_embed_gemm:     partials[kc][4096][256] = inputs @ emb_w   (bf16 MFMA, K split x5)
//   k_reduce_wx:      xw3[t][h][b] = ((sum_kc partials + emb_b) @ wx + hb)   (fp32)
//   k_rnn_scan:       512 sequential steps, 1 block x 8 waves; VALU-lean tanh
//                     (exp2+rcp), tanh spread across all 64 lanes via permlane32_swap,
//                     xw folded into MFMA C-init; single raw barrier/step
//   k_logits:         raw logits (+out_b) into ws, 64 blocks (8 vc x 8 b)
//   k_softmax8:       softmax over precomputed logits, 8 blocks

typedef float f32x4 __attribute__((ext_vector_type(4)));
typedef __bf16 bf16x8 __attribute__((ext_vector_type(8)));
typedef unsigned uint2v __attribute__((ext_vector_type(2)));

typedef const __attribute__((address_space(1))) void g_void;
typedef __attribute__((address_space(3))) void l_void;

#define BM 64
#define BN 256
#define BK 64
#define KSPLIT 5
#define KCH 1600   // 8000 / KSPLIT, = 25 * BK
#define NITER 25

// ---------------- transpose + f32->bf16 (64x64 tiles) ----------------
__global__ __launch_bounds__(256) void k_transpose_bf16(const float* __restrict__ in,
                                                        __bf16* __restrict__ out,
                                                        int R, int C) {
  __shared__ __bf16 lt[64][72];  // +8 pad
  const int tid = threadIdx.x;
  const int r0 = blockIdx.x * 64, c0 = blockIdx.y * 64;
  {
    const int rr = tid >> 2, cg = (tid & 3) * 16;
    const float* src = &in[(size_t)(r0 + rr) * C + c0 + cg];
#pragma unroll
    for (int u = 0; u < 16; u += 4) {
      f32x4 v = *(const f32x4*)(src + u);
      lt[rr][cg + u + 0] = (__bf16)v[0];
      lt[rr][cg + u + 1] = (__bf16)v[1];
      lt[rr][cg + u + 2] = (__bf16)v[2];
      lt[rr][cg + u + 3] = (__bf16)v[3];
    }
  }
  __syncthreads();
  {
    const int cc = tid >> 2, rg = (tid & 3) * 16;
    bf16x8 o0, o1;
#pragma unroll
    for (int e = 0; e < 8; ++e) o0[e] = lt[rg + e][cc];
#pragma unroll
    for (int e = 0; e < 8; ++e) o1[e] = lt[rg + 8 + e][cc];
    __bf16* dst = &out[(size_t)(c0 + cc) * R + r0 + rg];
    *(bf16x8*)(dst) = o0;
    *(bf16x8*)(dst + 8) = o1;
  }
}

// ---------------- embedding GEMM: partials[kc] = inputs @ emb_w ----------------
__global__ __launch_bounds__(512) void k_embed_gemm(const float* __restrict__ inp,
                                                    const __bf16* __restrict__ embT,
                                                    float* __restrict__ part) {
  __shared__ __bf16 sA[BM * BK];  // [row][k], elem idx ^ ((row&7)<<3)
  __shared__ __bf16 sB[BN * BK];  // [col][k], elem idx ^ ((col&7)<<3)
  const int tid = threadIdx.x;
  const int m0 = blockIdx.x * BM;
  const int kc = blockIdx.y;
  const size_t kbase0 = (size_t)kc * KCH;
  const int lane = tid & 63;
  const int w = tid >> 6;
  const int wm = w >> 2, wn = w & 3;
  const int l16 = lane & 15, lk = lane >> 4;

  const int ar = tid >> 3, ac = (tid & 7) * 8;   // A: 64 rows, 8 thr/row x 8 cols
  const int bc = tid >> 1, bk = (tid & 1) * 32;  // B: 256 cols, 2 thr/col x 32 k

  f32x4 acc[2][4] = {};

  const float* aptr = &inp[(size_t)(m0 + ar) * 8000 + kbase0 + ac];
  const __bf16* bptr = &embT[(size_t)bc * 8000 + kbase0 + bk];
  f32x4 a0 = *(const f32x4*)(aptr);
  f32x4 a1 = *(const f32x4*)(aptr + 4);
  bf16x8 b0 = *(const bf16x8*)(bptr);
  bf16x8 b1 = *(const bf16x8*)(bptr + 8);
  bf16x8 b2 = *(const bf16x8*)(bptr + 16);
  bf16x8 b3 = *(const bf16x8*)(bptr + 24);

  const int aswz = (ar & 7) << 3;
  const int bswz = (bc & 7) << 3;

  for (int it = 0; it < NITER; ++it) {
    __syncthreads();
    bf16x8 aw;
    aw[0] = (__bf16)a0[0]; aw[1] = (__bf16)a0[1]; aw[2] = (__bf16)a0[2]; aw[3] = (__bf16)a0[3];
    aw[4] = (__bf16)a1[0]; aw[5] = (__bf16)a1[1]; aw[6] = (__bf16)a1[2]; aw[7] = (__bf16)a1[3];
    *(bf16x8*)&sA[(ar * BK + ac) ^ aswz] = aw;
    *(bf16x8*)&sB[(bc * BK + bk + 0) ^ bswz] = b0;
    *(bf16x8*)&sB[(bc * BK + bk + 8) ^ bswz] = b1;
    *(bf16x8*)&sB[(bc * BK + bk + 16) ^ bswz] = b2;
    *(bf16x8*)&sB[(bc * BK + bk + 24) ^ bswz] = b3;
    __syncthreads();

    if (it + 1 < NITER) {
      const float* ap = aptr + (size_t)(it + 1) * BK;
      const __bf16* bp = bptr + (size_t)(it + 1) * BK;
      a0 = *(const f32x4*)(ap);
      a1 = *(const f32x4*)(ap + 4);
      b0 = *(const bf16x8*)(bp);
      b1 = *(const bf16x8*)(bp + 8);
      b2 = *(const bf16x8*)(bp + 16);
      b3 = *(const bf16x8*)(bp + 24);
    }

#pragma unroll
    for (int s = 0; s < 2; ++s) {
      bf16x8 af[2], bfb[4];
#pragma unroll
      for (int i = 0; i < 2; ++i) {
        const int r = wm * 32 + i * 16 + l16;
        af[i] = *(const bf16x8*)&sA[(r * BK + s * 32 + lk * 8) ^ ((r & 7) << 3)];
      }
#pragma unroll
      for (int j = 0; j < 4; ++j) {
        const int c = wn * 64 + j * 16 + l16;
        bfb[j] = *(const bf16x8*)&sB[(c * BK + s * 32 + lk * 8) ^ ((c & 7) << 3)];
      }
#pragma unroll
      for (int i = 0; i < 2; ++i)
#pragma unroll
        for (int j = 0; j < 4; ++j)
          acc[i][j] = __builtin_amdgcn_mfma_f32_16x16x32_bf16(af[i], bfb[j], acc[i][j], 0, 0, 0);
    }
  }

#pragma unroll
  for (int i = 0; i < 2; ++i)
#pragma unroll
    for (int j = 0; j < 4; ++j) {
#pragma unroll
      for (int e = 0; e < 4; ++e) {
        const int gr = m0 + wm * 32 + i * 16 + lk * 4 + e;
        const int gc = wn * 64 + j * 16 + l16;
        part[((size_t)kc * 4096 + gr) * 256 + gc] = acc[i][j][e];
      }
    }
}

// ---------------- reduce partials + emb_b, then @wx + hb -> xw3[t][h][b] ----------------
#define RW_MT 8
__global__ __launch_bounds__(256) void k_reduce_wx(const float* __restrict__ part,
                                                   const float* __restrict__ emb_b,
                                                   const float* __restrict__ wx,
                                                   const float* __restrict__ hb,
                                                   float* __restrict__ xw3) {
  __shared__ float xs[RW_MT][256];
  const int m0 = blockIdx.x * RW_MT;
  const int h = threadIdx.x;
  const float eb = emb_b[h];
#pragma unroll
  for (int mi = 0; mi < RW_MT; ++mi) {
    float s = eb;
#pragma unroll
    for (int c = 0; c < KSPLIT; ++c) s += part[((size_t)c * 4096 + m0 + mi) * 256 + h];
    xs[mi][h] = s;
  }
  __syncthreads();
  float acc[RW_MT];
  const float hbv = hb[h];
#pragma unroll
  for (int mi = 0; mi < RW_MT; ++mi) acc[mi] = hbv;
  for (int k = 0; k < 256; k += 4) {
    const float w0 = wx[(k + 0) * 256 + h];
    const float w1 = wx[(k + 1) * 256 + h];
    const float w2 = wx[(k + 2) * 256 + h];
    const float w3 = wx[(k + 3) * 256 + h];
#pragma unroll
    for (int mi = 0; mi < RW_MT; ++mi) {
      f32x4 xv = *(const f32x4*)&xs[mi][k];
      acc[mi] += xv[0] * w0 + xv[1] * w1 + xv[2] * w2 + xv[3] * w3;
    }
  }
#pragma unroll
  for (int mi = 0; mi < RW_MT; ++mi) {
    const int m = m0 + mi;
    const int b = m >> 9, t = m & 511;
    xw3[((size_t)t * 256 + h) * 8 + b] = acc[mi];  // [t][h][b]
  }
}

// ---------------- sequential RNN scan ----------------
// 1 block x 512 threads (8 waves); wave w owns cols [w*32, w*32+32) (2 col-tiles).
// wh as static B-frags in regs; h double-buffered in LDS (8x256 bf16, XOR-swizzled);
// xw staged 8 steps/chunk into a 2-buffer LDS ring via global_load_lds (counted vmcnt);
// xv folded into MFMA C-init; tanh = 1 - 2*rcp(exp2(2log2e*v)+1) spread over all 64
// lanes via v_permlane32_swap; one raw s_barrier per step.
__device__ __forceinline__ void gload_lds16(const float* g, float* l) {
  __builtin_amdgcn_global_load_lds((g_void*)g, (l_void*)l, 16, 0, 0);
}

__device__ __forceinline__ void swap_half(float& x, float& y) {
  uint2v r = __builtin_amdgcn_permlane32_swap(__float_as_uint(x), __float_as_uint(y),
                                              false, false);
  x = __uint_as_float(r[0]);
  y = __uint_as_float(r[1]);
}

__global__ __launch_bounds__(512) void k_rnn_scan(const __bf16* __restrict__ whT,
                                                  const float* __restrict__ xw3,
                                                  float* __restrict__ hT) {
  __shared__ __bf16 hA[2][8 * 256];     // 8 KB
  __shared__ float ring[2][8 * 2048];   // 128 KB (8 steps x [h][b] per buffer)
  const int tid = threadIdx.x;
  const int lane = tid & 63;
  const int w = tid >> 6;               // 0..7
  const int l16 = lane & 15, lk = lane >> 4;
  const bool rdact = (l16 < 8);         // lanes holding valid (nonzero) A rows
  const bool xact = (lk < 2);           // lanes with valid C rows (b = lk*4+e < 8)

  // post-redistribution ownership: all 64 lanes, 4 elems each
  const int myb4 = (lk & 1) * 4;
  const int mycol = w * 32 + ((lk >= 2) ? 16 : 0) + l16;

  // static B fragments: wh[k][col] for 2 col-tiles
  bf16x8 whB[2][8];
#pragma unroll
  for (int j = 0; j < 2; ++j) {
    const int col = w * 32 + j * 16 + l16;
#pragma unroll
    for (int s = 0; s < 8; ++s)
      whB[j][s] = *(const bf16x8*)&whT[(size_t)col * 256 + s * 32 + lk * 8];
  }

  // zero h buffer 0
  for (int i = tid; i < 8 * 256; i += 512) hA[0][i] = (__bf16)0.0f;

  // stage chunk 0 into ring[0]
  {
    const float* src = xw3 + (size_t)w * 2048 + lane * 4;
#pragma unroll
    for (int i = 0; i < 8; ++i)
      gload_lds16(src + i * 256, &ring[0][w * 2048 + i * 256]);
  }
  asm volatile("s_waitcnt vmcnt(0)" ::: "memory");
  __syncthreads();

  bf16x8 af[8];
#pragma unroll
  for (int s = 0; s < 8; ++s) af[s] = bf16x8{};

  for (int t = 0; t < 512; ++t) {
    const int cur = t & 1;
    const int rb = (t >> 3) & 1;

    // ---- read phase: A-frags of h (masked to valid rows) + this step's xw
    if (rdact) {
#pragma unroll
      for (int s = 0; s < 8; ++s)
        af[s] = *(const bf16x8*)&hA[cur][(l16 * 256 + s * 32 + lk * 8) ^ (l16 << 3)];
    }
    f32x4 xv[2];
#pragma unroll
    for (int j = 0; j < 2; ++j) {
      xv[j] = f32x4{};
      if (xact) {
        const int col = w * 32 + j * 16 + l16;
        xv[j] = *(const f32x4*)&ring[rb][(t & 7) * 2048 + col * 8 + lk * 4];
      }
    }

    // ---- issue next-chunk staging (completes ~7 steps later; never drained hot)
    if ((t & 7) == 0 && t + 8 < 512) {
      const int c1 = (t >> 3) + 1;
      const int nb = c1 & 1;
      const float* src = xw3 + (size_t)c1 * 16384 + w * 2048 + lane * 4;
#pragma unroll
      for (int i = 0; i < 8; ++i)
        gload_lds16(src + i * 256, &ring[nb][w * 2048 + i * 256]);
    }

    // ---- compute: 2 col-tiles, K split into 4 partial accs (chain depth 2); xv = C-init
    f32x4 o[2];
#pragma unroll
    for (int j = 0; j < 2; ++j) {
      f32x4 p0 = xv[j], p1 = {}, p2 = {}, p3 = {};
      p0 = __builtin_amdgcn_mfma_f32_16x16x32_bf16(af[0], whB[j][0], p0, 0, 0, 0);
      p1 = __builtin_amdgcn_mfma_f32_16x16x32_bf16(af[1], whB[j][1], p1, 0, 0, 0);
      p2 = __builtin_amdgcn_mfma_f32_16x16x32_bf16(af[2], whB[j][2], p2, 0, 0, 0);
      p3 = __builtin_amdgcn_mfma_f32_16x16x32_bf16(af[3], whB[j][3], p3, 0, 0, 0);
      p0 = __builtin_amdgcn_mfma_f32_16x16x32_bf16(af[4], whB[j][4], p0, 0, 0, 0);
      p1 = __builtin_amdgcn_mfma_f32_16x16x32_bf16(af[5], whB[j][5], p1, 0, 0, 0);
      p2 = __builtin_amdgcn_mfma_f32_16x16x32_bf16(af[6], whB[j][6], p2, 0, 0, 0);
      p3 = __builtin_amdgcn_mfma_f32_16x16x32_bf16(af[7], whB[j][7], p3, 0, 0, 0);
      o[j] = (p0 + p1) + (p2 + p3);
    }

    // ---- redistribute: lanes 0-31 keep tile0, lanes 32-63 get tile1
    f32x4 mine;
#pragma unroll
    for (int e = 0; e < 4; ++e) {
      float x = o[0][e], y = o[1][e];
      swap_half(x, y);
      mine[e] = x;
    }

    // ---- tanh (5 VALU/elem) + write new h; all 64 lanes, 4 elems each
#pragma unroll
    for (int e = 0; e < 4; ++e) {
      const float v = mine[e];
      const float e2 = __builtin_amdgcn_exp2f(v * 2.8853900817779268f);  // e^(2v)
      const float hn = __builtin_fmaf(-2.0f, __builtin_amdgcn_rcpf(e2 + 1.0f), 1.0f);
      const int b = myb4 + e;
      hA[cur ^ 1][(b * 256 + mycol) ^ (b << 3)] = (__bf16)hn;
      if (t == 511) hT[b * 256 + mycol] = hn;
    }

    // ---- chunk boundary: ensure next ring buffer is filled (issued 7 steps ago)
    if ((t & 7) == 7) asm volatile("s_waitcnt vmcnt(0)" ::: "memory");
    // ---- single barrier per step
    asm volatile("s_waitcnt lgkmcnt(0)" ::: "memory");
    __builtin_amdgcn_sched_barrier(0);
    __builtin_amdgcn_s_barrier();
    __builtin_amdgcn_sched_barrier(0);
  }
}

// ---------------- logits: raw logits (+out_b) -> ws, 64 blocks ----------------
// grid (vc=8, b=8); block 256 threads; thread computes 4 consecutive v.
__global__ __launch_bounds__(256) void k_logits(const float* __restrict__ hT,
                                                const float* __restrict__ out_w,
                                                const float* __restrict__ out_b,
                                                float* __restrict__ logits) {
  __shared__ float hs[256];
  const int vc = blockIdx.x, b = blockIdx.y;
  const int tid = threadIdx.x;
  hs[tid] = hT[b * 256 + tid];
  __syncthreads();

  const int v0 = vc * 1024 + tid * 4;
  if (v0 >= 8000) return;
  f32x4 acc = *(const f32x4*)&out_b[v0];
#pragma unroll 4
  for (int k = 0; k < 256; ++k) {
    acc += hs[k] * (*(const f32x4*)&out_w[(size_t)k * 8000 + v0]);
  }
  *(f32x4*)&logits[(size_t)b * 8192 + v0] = acc;
}

// ---------------- softmax over precomputed logits, 8 blocks ----------------
__global__ __launch_bounds__(1024) void k_softmax8(const float* __restrict__ logits,
                                                   float* __restrict__ out) {
  __shared__ float red[16];
  const int b = blockIdx.x;
  const int tid = threadIdx.x;
  const bool active = tid < 1000;
  const int v0 = tid * 8;
  f32x4 acc0 = {}, acc1 = {};
  if (active) {
    acc0 = *(const f32x4*)&logits[(size_t)b * 8192 + v0];
    acc1 = *(const f32x4*)&logits[(size_t)b * 8192 + v0 + 4];
  }

  float m = -__builtin_huge_valf();
  if (active) {
#pragma unroll
    for (int e = 0; e < 4; ++e) m = fmaxf(m, fmaxf(acc0[e], acc1[e]));
  }
#pragma unroll
  for (int off = 32; off > 0; off >>= 1) m = fmaxf(m, __shfl_xor(m, off));
  if ((tid & 63) == 0) red[tid >> 6] = m;
  __syncthreads();
  if (tid < 64) {
    float t = (tid < 16) ? red[tid] : -__builtin_huge_valf();
#pragma unroll
    for (int off = 8; off > 0; off >>= 1) t = fmaxf(t, __shfl_xor(t, off));
    if (tid == 0) red[0] = t;
  }
  __syncthreads();
  const float M = red[0];

  f32x4 e0 = {}, e1 = {};
  float s = 0.0f;
  if (active) {
#pragma unroll
    for (int e = 0; e < 4; ++e) {
      e0[e] = __expf(acc0[e] - M);
      e1[e] = __expf(acc1[e] - M);
      s += e0[e] + e1[e];
    }
  }
#pragma unroll
  for (int off = 32; off > 0; off >>= 1) s += __shfl_xor(s, off);
  if ((tid & 63) == 0) red[tid >> 6] = s;
  __syncthreads();
  if (tid < 64) {
    float t = (tid < 16) ? red[tid] : 0.0f;
#pragma unroll
    for (int off = 8; off > 0; off >>= 1) t += __shfl_xor(t, off);
    if (tid == 0) red[0] = t;
  }
  __syncthreads();
  const float inv = 1.0f / red[0];

  if (active) {
    float* op = &out[(size_t)b * 8000 + v0];
    *(f32x4*)(op) = e0 * inv;
    *(f32x4*)(op + 4) = e1 * inv;
  }
}

// ---------------- launch ----------------
extern "C" void kernel_launch(void* const* d_in, const int* in_sizes, int n_in,
                              void* d_out, int out_size, void* d_ws, size_t ws_size,
                              hipStream_t stream) {
  const float* inputs = (const float*)d_in[0];  // (8,512,8000)
  const float* emb_w  = (const float*)d_in[1];  // (8000,256)
  const float* emb_b  = (const float*)d_in[2];  // (256)
  const float* wx     = (const float*)d_in[3];  // (256,256)
  const float* wh     = (const float*)d_in[4];  // (256,256)
  const float* hb     = (const float*)d_in[5];  // (1,256)
  const float* out_w  = (const float*)d_in[6];  // (256,8000)
  const float* out_b  = (const float*)d_in[7];  // (8000)
  float* out = (float*)d_out;                   // (8,1,8000)

  char* ws = (char*)d_ws;
  __bf16* embT  = (__bf16*)(ws + 0);              // 256x8000 bf16 = 4,096,000 B
  __bf16* whT   = (__bf16*)(ws + 4096000);        // 256x256 bf16  =   131,072 B
  float* part   = (float*)(ws + 4227072);         // 5x4096x256 f32 = 20,971,520 B
  float* xw3    = (float*)(ws + 25198592);        // [512][256][8] f32 = 4,194,304 B
  float* hT     = (float*)(ws + 29392896);        // 8x256 f32     =      8,192 B
  float* logits = (float*)(ws + 29401088);        // 8x8192 f32    =    262,144 B

  k_transpose_bf16<<<dim3(125, 4), 256, 0, stream>>>(emb_w, embT, 8000, 256);
  k_transpose_bf16<<<dim3(4, 4), 256, 0, stream>>>(wh, whT, 256, 256);
  k_embed_gemm<<<dim3(64, KSPLIT), 512, 0, stream>>>(inputs, embT, part);
  k_reduce_wx<<<512, 256, 0, stream>>>(part, emb_b, wx, hb, xw3);
  k_rnn_scan<<<1, 512, 0, stream>>>(whT, xw3, hT);
  k_logits<<<dim3(8, 8), 256, 0, stream>>>(hT, out_w, out_b, logits);
  k_softmax8<<<8, 1024, 0, stream>>>(logits, out);
}

// Round 5
// 618.178 us; speedup vs baseline: 1.8579x; 1.1216x over previous
//
#include <hip/hip_runtime.h>
#include <cmath>

// B=8, N=512, V=8000, H=256
// Pipeline:
//   k_transpose_bf16: emb_w (8000x256 f32) -> embT (256x8000 bf16); wh -> whT
//   k_embed_gemm:     partials[kc][4096][256] = inputs @ emb_w   (bf16 MFMA, K split x5)
//   k_reduce_wx:      xw4[b][t][h] = ((sum_kc partials + emb_b) @ wx + hb)   (fp32)
//   k_rnn_scan:       per-batch recurrence, 8 blocks (1 CU each) x 4 waves;
//                     GEMV via MFMA row-0, wh in regs, h in 2x256 bf16 LDS,
//                     xw prefetch distance-2 via manual 2-unroll
//   k_logits:         raw logits (+out_b) into ws, 64 blocks (8 vc x 8 b)
//   k_softmax8:       softmax over precomputed logits, 8 blocks

typedef float f32x4 __attribute__((ext_vector_type(4)));
typedef __bf16 bf16x8 __attribute__((ext_vector_type(8)));

#define BM 64
#define BN 256
#define BK 64
#define KSPLIT 5
#define KCH 1600   // 8000 / KSPLIT, = 25 * BK
#define NITER 25

// ---------------- transpose + f32->bf16 (64x64 tiles) ----------------
__global__ __launch_bounds__(256) void k_transpose_bf16(const float* __restrict__ in,
                                                        __bf16* __restrict__ out,
                                                        int R, int C) {
  __shared__ __bf16 lt[64][72];  // +8 pad
  const int tid = threadIdx.x;
  const int r0 = blockIdx.x * 64, c0 = blockIdx.y * 64;
  {
    const int rr = tid >> 2, cg = (tid & 3) * 16;
    const float* src = &in[(size_t)(r0 + rr) * C + c0 + cg];
#pragma unroll
    for (int u = 0; u < 16; u += 4) {
      f32x4 v = *(const f32x4*)(src + u);
      lt[rr][cg + u + 0] = (__bf16)v[0];
      lt[rr][cg + u + 1] = (__bf16)v[1];
      lt[rr][cg + u + 2] = (__bf16)v[2];
      lt[rr][cg + u + 3] = (__bf16)v[3];
    }
  }
  __syncthreads();
  {
    const int cc = tid >> 2, rg = (tid & 3) * 16;
    bf16x8 o0, o1;
#pragma unroll
    for (int e = 0; e < 8; ++e) o0[e] = lt[rg + e][cc];
#pragma unroll
    for (int e = 0; e < 8; ++e) o1[e] = lt[rg + 8 + e][cc];
    __bf16* dst = &out[(size_t)(c0 + cc) * R + r0 + rg];
    *(bf16x8*)(dst) = o0;
    *(bf16x8*)(dst + 8) = o1;
  }
}

// ---------------- embedding GEMM: partials[kc] = inputs @ emb_w ----------------
__global__ __launch_bounds__(512) void k_embed_gemm(const float* __restrict__ inp,
                                                    const __bf16* __restrict__ embT,
                                                    float* __restrict__ part) {
  __shared__ __bf16 sA[BM * BK];  // [row][k], elem idx ^ ((row&7)<<3)
  __shared__ __bf16 sB[BN * BK];  // [col][k], elem idx ^ ((col&7)<<3)
  const int tid = threadIdx.x;
  const int m0 = blockIdx.x * BM;
  const int kc = blockIdx.y;
  const size_t kbase0 = (size_t)kc * KCH;
  const int lane = tid & 63;
  const int w = tid >> 6;
  const int wm = w >> 2, wn = w & 3;
  const int l16 = lane & 15, lk = lane >> 4;

  const int ar = tid >> 3, ac = (tid & 7) * 8;   // A: 64 rows, 8 thr/row x 8 cols
  const int bc = tid >> 1, bk = (tid & 1) * 32;  // B: 256 cols, 2 thr/col x 32 k

  f32x4 acc[2][4] = {};

  const float* aptr = &inp[(size_t)(m0 + ar) * 8000 + kbase0 + ac];
  const __bf16* bptr = &embT[(size_t)bc * 8000 + kbase0 + bk];
  f32x4 a0 = *(const f32x4*)(aptr);
  f32x4 a1 = *(const f32x4*)(aptr + 4);
  bf16x8 b0 = *(const bf16x8*)(bptr);
  bf16x8 b1 = *(const bf16x8*)(bptr + 8);
  bf16x8 b2 = *(const bf16x8*)(bptr + 16);
  bf16x8 b3 = *(const bf16x8*)(bptr + 24);

  const int aswz = (ar & 7) << 3;
  const int bswz = (bc & 7) << 3;

  for (int it = 0; it < NITER; ++it) {
    __syncthreads();
    bf16x8 aw;
    aw[0] = (__bf16)a0[0]; aw[1] = (__bf16)a0[1]; aw[2] = (__bf16)a0[2]; aw[3] = (__bf16)a0[3];
    aw[4] = (__bf16)a1[0]; aw[5] = (__bf16)a1[1]; aw[6] = (__bf16)a1[2]; aw[7] = (__bf16)a1[3];
    *(bf16x8*)&sA[(ar * BK + ac) ^ aswz] = aw;
    *(bf16x8*)&sB[(bc * BK + bk + 0) ^ bswz] = b0;
    *(bf16x8*)&sB[(bc * BK + bk + 8) ^ bswz] = b1;
    *(bf16x8*)&sB[(bc * BK + bk + 16) ^ bswz] = b2;
    *(bf16x8*)&sB[(bc * BK + bk + 24) ^ bswz] = b3;
    __syncthreads();

    if (it + 1 < NITER) {
      const float* ap = aptr + (size_t)(it + 1) * BK;
      const __bf16* bp = bptr + (size_t)(it + 1) * BK;
      a0 = *(const f32x4*)(ap);
      a1 = *(const f32x4*)(ap + 4);
      b0 = *(const bf16x8*)(bp);
      b1 = *(const bf16x8*)(bp + 8);
      b2 = *(const bf16x8*)(bp + 16);
      b3 = *(const bf16x8*)(bp + 24);
    }

#pragma unroll
    for (int s = 0; s < 2; ++s) {
      bf16x8 af[2], bfb[4];
#pragma unroll
      for (int i = 0; i < 2; ++i) {
        const int r = wm * 32 + i * 16 + l16;
        af[i] = *(const bf16x8*)&sA[(r * BK + s * 32 + lk * 8) ^ ((r & 7) << 3)];
      }
#pragma unroll
      for (int j = 0; j < 4; ++j) {
        const int c = wn * 64 + j * 16 + l16;
        bfb[j] = *(const bf16x8*)&sB[(c * BK + s * 32 + lk * 8) ^ ((c & 7) << 3)];
      }
#pragma unroll
      for (int i = 0; i < 2; ++i)
#pragma unroll
        for (int j = 0; j < 4; ++j)
          acc[i][j] = __builtin_amdgcn_mfma_f32_16x16x32_bf16(af[i], bfb[j], acc[i][j], 0, 0, 0);
    }
  }

#pragma unroll
  for (int i = 0; i < 2; ++i)
#pragma unroll
    for (int j = 0; j < 4; ++j) {
#pragma unroll
      for (int e = 0; e < 4; ++e) {
        const int gr = m0 + wm * 32 + i * 16 + lk * 4 + e;
        const int gc = wn * 64 + j * 16 + l16;
        part[((size_t)kc * 4096 + gr) * 256 + gc] = acc[i][j][e];
      }
    }
}

// ---------------- reduce partials + emb_b, then @wx + hb -> xw4[b][t][h] ----------------
#define RW_MT 16
__global__ __launch_bounds__(256) void k_reduce_wx(const float* __restrict__ part,
                                                   const float* __restrict__ emb_b,
                                                   const float* __restrict__ wx,
                                                   const float* __restrict__ hb,
                                                   float* __restrict__ xw4) {
  __shared__ float xs[RW_MT][256];
  const int m0 = blockIdx.x * RW_MT;
  const int h = threadIdx.x;
  const float eb = emb_b[h];
#pragma unroll
  for (int mi = 0; mi < RW_MT; ++mi) {
    float s = eb;
#pragma unroll
    for (int c = 0; c < KSPLIT; ++c) s += part[((size_t)c * 4096 + m0 + mi) * 256 + h];
    xs[mi][h] = s;
  }
  __syncthreads();
  float acc[RW_MT];
  const float hbv = hb[h];
#pragma unroll
  for (int mi = 0; mi < RW_MT; ++mi) acc[mi] = hbv;
  for (int k = 0; k < 256; k += 4) {
    const float w0 = wx[(k + 0) * 256 + h];
    const float w1 = wx[(k + 1) * 256 + h];
    const float w2 = wx[(k + 2) * 256 + h];
    const float w3 = wx[(k + 3) * 256 + h];
#pragma unroll
    for (int mi = 0; mi < RW_MT; ++mi) {
      f32x4 xv = *(const f32x4*)&xs[mi][k];
      acc[mi] += xv[0] * w0 + xv[1] * w1 + xv[2] * w2 + xv[3] * w3;
    }
  }
#pragma unroll
  for (int mi = 0; mi < RW_MT; ++mi) {
    const int m = m0 + mi;
    const int b = m >> 9, t = m & 511;
    xw4[((size_t)b * 512 + t) * 256 + h] = acc[mi];  // [b][t][h]
  }
}

// ---------------- sequential RNN scan: per-batch, 8 blocks ----------------
// block b handles batch b. 256 threads = 4 waves; wave w owns cols [w*64, w*64+64)
// as 4 16-col MFMA tiles. h lives in LDS as bf16[2][256] (double-buffered).
// A-frag: only row 0 is real (lanes l16==0 read h, other lanes stay zero).
// C row 0 (lk==0, e==0) is the GEMV output; xv folded into C-init.
// One 4-wave barrier per step; xw prefetched distance-2 via manual 2-unroll.
__global__ __launch_bounds__(256, 1) void k_rnn_scan(const __bf16* __restrict__ whT,
                                                     const float* __restrict__ xw4,
                                                     float* __restrict__ hT) {
  __shared__ __bf16 h2[2][256];
  const int tid = threadIdx.x;
  const int lane = tid & 63;
  const int w = tid >> 6;            // 0..3
  const int l16 = lane & 15, lk = lane >> 4;
  const int b = blockIdx.x;
  const bool act = (l16 == 0);       // A-provider lanes (4 per wave)
  const bool oact = (lk == 0);       // C-row-0 lanes (16 per wave)
  const int colb = w * 64 + l16;     // col of tile j = colb + j*16

  // wh B-fragments in registers: whB[j][s] = wh[k=s*32+lk*8 ..][col=colb+j*16]
  bf16x8 whB[4][8];
#pragma unroll
  for (int j = 0; j < 4; ++j) {
    const int col = colb + j * 16;
#pragma unroll
    for (int s = 0; s < 8; ++s)
      whB[j][s] = *(const bf16x8*)&whT[(size_t)col * 256 + s * 32 + lk * 8];
  }

  h2[0][tid] = (__bf16)0.0f;  // zero initial h (buffer 0); buffer 1 fully written each odd step

  const float* xwb = &xw4[(size_t)b * 512 * 256];
  float xvA[4], xvB[4], nA[4], nB[4];
#pragma unroll
  for (int j = 0; j < 4; ++j) {
    xvA[j] = xwb[0 * 256 + colb + j * 16];
    xvB[j] = xwb[1 * 256 + colb + j * 16];
  }

  bf16x8 af[8];
#pragma unroll
  for (int s = 0; s < 8; ++s) af[s] = bf16x8{};  // inactive lanes stay 0 forever

  __syncthreads();

#define RNN_STEP(RD, WR, XV, LAST_T)                                              \
  {                                                                               \
    if (act) {                                                                    \
      _Pragma("unroll") for (int s = 0; s < 8; ++s)                               \
          af[s] = *(const bf16x8*)&h2[RD][s * 32 + lk * 8];                       \
    }                                                                             \
    float hn[4];                                                                  \
    _Pragma("unroll") for (int j = 0; j < 4; ++j) {                               \
      f32x4 pA = {}, pB = {};                                                     \
      pA[0] = oact ? (XV)[j] : 0.0f;                                              \
      pA = __builtin_amdgcn_mfma_f32_16x16x32_bf16(af[0], whB[j][0], pA, 0, 0, 0);\
      pB = __builtin_amdgcn_mfma_f32_16x16x32_bf16(af[1], whB[j][1], pB, 0, 0, 0);\
      pA = __builtin_amdgcn_mfma_f32_16x16x32_bf16(af[2], whB[j][2], pA, 0, 0, 0);\
      pB = __builtin_amdgcn_mfma_f32_16x16x32_bf16(af[3], whB[j][3], pB, 0, 0, 0);\
      pA = __builtin_amdgcn_mfma_f32_16x16x32_bf16(af[4], whB[j][4], pA, 0, 0, 0);\
      pB = __builtin_amdgcn_mfma_f32_16x16x32_bf16(af[5], whB[j][5], pB, 0, 0, 0);\
      pA = __builtin_amdgcn_mfma_f32_16x16x32_bf16(af[6], whB[j][6], pA, 0, 0, 0);\
      pB = __builtin_amdgcn_mfma_f32_16x16x32_bf16(af[7], whB[j][7], pB, 0, 0, 0);\
      const float v = pA[0] + pB[0];                                              \
      const float e2 = __builtin_amdgcn_exp2f(v * 2.8853900817779268f);           \
      hn[j] = __builtin_fmaf(-2.0f, __builtin_amdgcn_rcpf(e2 + 1.0f), 1.0f);      \
    }                                                                             \
    if (oact) {                                                                   \
      _Pragma("unroll") for (int j = 0; j < 4; ++j) {                             \
        h2[WR][colb + j * 16] = (__bf16)hn[j];                                    \
        if (LAST_T) hT[b * 256 + colb + j * 16] = hn[j];                          \
      }                                                                           \
    }                                                                             \
    asm volatile("s_waitcnt lgkmcnt(0)" ::: "memory");                            \
    __builtin_amdgcn_sched_barrier(0);                                            \
    __builtin_amdgcn_s_barrier();                                                 \
    __builtin_amdgcn_sched_barrier(0);                                            \
  }

  for (int tt = 0; tt < 256; ++tt) {
    const int t0 = tt * 2;
    const bool more = (tt < 255);
    // prefetch for t0+2 (distance 2: consumed one full iteration later)
    if (more) {
#pragma unroll
      for (int j = 0; j < 4; ++j) nA[j] = xwb[(size_t)(t0 + 2) * 256 + colb + j * 16];
    }
    RNN_STEP(0, 1, xvA, false)
    if (more) {
#pragma unroll
      for (int j = 0; j < 4; ++j) nB[j] = xwb[(size_t)(t0 + 3) * 256 + colb + j * 16];
    }
    RNN_STEP(1, 0, xvB, (tt == 255))
    if (more) {
#pragma unroll
      for (int j = 0; j < 4; ++j) { xvA[j] = nA[j]; xvB[j] = nB[j]; }
    }
  }
#undef RNN_STEP
}

// ---------------- logits: raw logits (+out_b) -> ws, 64 blocks ----------------
__global__ __launch_bounds__(256) void k_logits(const float* __restrict__ hT,
                                                const float* __restrict__ out_w,
                                                const float* __restrict__ out_b,
                                                float* __restrict__ logits) {
  __shared__ float hs[256];
  const int vc = blockIdx.x, b = blockIdx.y;
  const int tid = threadIdx.x;
  hs[tid] = hT[b * 256 + tid];
  __syncthreads();

  const int v0 = vc * 1024 + tid * 4;
  if (v0 >= 8000) return;
  f32x4 acc = *(const f32x4*)&out_b[v0];
#pragma unroll 4
  for (int k = 0; k < 256; ++k) {
    acc += hs[k] * (*(const f32x4*)&out_w[(size_t)k * 8000 + v0]);
  }
  *(f32x4*)&logits[(size_t)b * 8192 + v0] = acc;
}

// ---------------- softmax over precomputed logits, 8 blocks ----------------
__global__ __launch_bounds__(1024) void k_softmax8(const float* __restrict__ logits,
                                                   float* __restrict__ out) {
  __shared__ float red[16];
  const int b = blockIdx.x;
  const int tid = threadIdx.x;
  const bool active = tid < 1000;
  const int v0 = tid * 8;
  f32x4 acc0 = {}, acc1 = {};
  if (active) {
    acc0 = *(const f32x4*)&logits[(size_t)b * 8192 + v0];
    acc1 = *(const f32x4*)&logits[(size_t)b * 8192 + v0 + 4];
  }

  float m = -__builtin_huge_valf();
  if (active) {
#pragma unroll
    for (int e = 0; e < 4; ++e) m = fmaxf(m, fmaxf(acc0[e], acc1[e]));
  }
#pragma unroll
  for (int off = 32; off > 0; off >>= 1) m = fmaxf(m, __shfl_xor(m, off));
  if ((tid & 63) == 0) red[tid >> 6] = m;
  __syncthreads();
  if (tid < 64) {
    float t = (tid < 16) ? red[tid] : -__builtin_huge_valf();
#pragma unroll
    for (int off = 8; off > 0; off >>= 1) t = fmaxf(t, __shfl_xor(t, off));
    if (tid == 0) red[0] = t;
  }
  __syncthreads();
  const float M = red[0];

  f32x4 e0 = {}, e1 = {};
  float s = 0.0f;
  if (active) {
#pragma unroll
    for (int e = 0; e < 4; ++e) {
      e0[e] = __expf(acc0[e] - M);
      e1[e] = __expf(acc1[e] - M);
      s += e0[e] + e1[e];
    }
  }
#pragma unroll
  for (int off = 32; off > 0; off >>= 1) s += __shfl_xor(s, off);
  if ((tid & 63) == 0) red[tid >> 6] = s;
  __syncthreads();
  if (tid < 64) {
    float t = (tid < 16) ? red[tid] : 0.0f;
#pragma unroll
    for (int off = 8; off > 0; off >>= 1) t += __shfl_xor(t, off);
    if (tid == 0) red[0] = t;
  }
  __syncthreads();
  const float inv = 1.0f / red[0];

  if (active) {
    float* op = &out[(size_t)b * 8000 + v0];
    *(f32x4*)(op) = e0 * inv;
    *(f32x4*)(op + 4) = e1 * inv;
  }
}

// ---------------- launch ----------------
extern "C" void kernel_launch(void* const* d_in, const int* in_sizes, int n_in,
                              void* d_out, int out_size, void* d_ws, size_t ws_size,
                              hipStream_t stream) {
  const float* inputs = (const float*)d_in[0];  // (8,512,8000)
  const float* emb_w  = (const float*)d_in[1];  // (8000,256)
  const float* emb_b  = (const float*)d_in[2];  // (256)
  const float* wx     = (const float*)d_in[3];  // (256,256)
  const float* wh     = (const float*)d_in[4];  // (256,256)
  const float* hb     = (const float*)d_in[5];  // (1,256)
  const float* out_w  = (const float*)d_in[6];  // (256,8000)
  const float* out_b  = (const float*)d_in[7];  // (8000)
  float* out = (float*)d_out;                   // (8,1,8000)

  char* ws = (char*)d_ws;
  __bf16* embT  = (__bf16*)(ws + 0);              // 256x8000 bf16 = 4,096,000 B
  __bf16* whT   = (__bf16*)(ws + 4096000);        // 256x256 bf16  =   131,072 B
  float* part   = (float*)(ws + 4227072);         // 5x4096x256 f32 = 20,971,520 B
  float* xw4    = (float*)(ws + 25198592);        // [8][512][256] f32 = 4,194,304 B
  float* hT     = (float*)(ws + 29392896);        // 8x256 f32     =      8,192 B
  float* logits = (float*)(ws + 29401088);        // 8x8192 f32    =    262,144 B

  k_transpose_bf16<<<dim3(125, 4), 256, 0, stream>>>(emb_w, embT, 8000, 256);
  k_transpose_bf16<<<dim3(4, 4), 256, 0, stream>>>(wh, whT, 256, 256);
  k_embed_gemm<<<dim3(64, KSPLIT), 512, 0, stream>>>(inputs, embT, part);
  k_reduce_wx<<<256, 256, 0, stream>>>(part, emb_b, wx, hb, xw4);
  k_rnn_scan<<<8, 256, 0, stream>>>(whT, xw4, hT);
  k_logits<<<dim3(8, 8), 256, 0, stream>>>(hT, out_w, out_b, logits);
  k_softmax8<<<8, 1024, 0, stream>>>(logits, out);
}

// Round 7
// 581.245 us; speedup vs baseline: 1.9759x; 1.0635x over previous
//
#include <hip/hip_runtime.h>
#include <cmath>

// B=8, N=512, V=8000, H=256
// Algebraic fusion: xw = inputs @ W2 + c2, where W2 = emb_w@wx, c2 = emb_b@wx + hb.
// Pipeline:
//   k_transpose_bf16: wh -> whT, wx -> wxT (bf16, tiny)
//   k_w2m:      W2T[h][v] = (wxT @ emb_w^T) via MFMA (emb_w rows are already k-contig)
//   k_c2:       c2[h] = emb_b@wx + hb (fp32)
//   k_embed_gemm2: part[kc][4096][256] = inputs @ W2  (bf16 MFMA, KSPLIT=5, BM=32,
//               double-buffered LDS, 1 barrier/iter, distance-2 register prefetch)
//   k_reduce2:  xw4[b][t][h] = sum_kc part + c2
//   k_rnn_scan: 2 dispatches x 256 steps (h handoff via hT), per-batch blocks
//   k_logits / k_softmax8

typedef float f32x4 __attribute__((ext_vector_type(4)));
typedef __bf16 bf16x4 __attribute__((ext_vector_type(4)));
typedef __bf16 bf16x8 __attribute__((ext_vector_type(8)));

#define KSPLIT 5
#define KCH 1600
#define NITER 25   // KCH / 64

// ---------------- transpose + f32->bf16 (64x64 tiles) ----------------
__global__ __launch_bounds__(256) void k_transpose_bf16(const float* __restrict__ in,
                                                        __bf16* __restrict__ out,
                                                        int R, int C) {
  __shared__ __bf16 lt[64][72];
  const int tid = threadIdx.x;
  const int r0 = blockIdx.x * 64, c0 = blockIdx.y * 64;
  {
    const int rr = tid >> 2, cg = (tid & 3) * 16;
    const float* src = &in[(size_t)(r0 + rr) * C + c0 + cg];
#pragma unroll
    for (int u = 0; u < 16; u += 4) {
      f32x4 v = *(const f32x4*)(src + u);
      lt[rr][cg + u + 0] = (__bf16)v[0];
      lt[rr][cg + u + 1] = (__bf16)v[1];
      lt[rr][cg + u + 2] = (__bf16)v[2];
      lt[rr][cg + u + 3] = (__bf16)v[3];
    }
  }
  __syncthreads();
  {
    const int cc = tid >> 2, rg = (tid & 3) * 16;
    bf16x8 o0, o1;
#pragma unroll
    for (int e = 0; e < 8; ++e) o0[e] = lt[rg + e][cc];
#pragma unroll
    for (int e = 0; e < 8; ++e) o1[e] = lt[rg + 8 + e][cc];
    __bf16* dst = &out[(size_t)(c0 + cc) * R + r0 + rg];
    *(bf16x8*)(dst) = o0;
    *(bf16x8*)(dst + 8) = o1;
  }
}

// ---------------- W2T = wxT @ emb_w^T : [256 h][8000 v] bf16 ----------------
// A = wxT bf16 [256][256] (k-contig); B = emb_w f32 [8000][256] (rows = v, k-contig).
// 125 blocks (64 v each), 512 thr = 8 waves (4M x 2N), wave tile 64h x 32v, K=256 (4 iters).
__global__ __launch_bounds__(512) void k_w2m(const __bf16* __restrict__ wxT,
                                             const float* __restrict__ emb_w,
                                             __bf16* __restrict__ w2t) {
  __shared__ __bf16 sA[256 * 64];  // [h][k] ^ ((h&7)<<3)
  __shared__ __bf16 sB[64 * 64];   // [v][k] ^ ((v&7)<<3)
  const int tid = threadIdx.x;
  const int v0 = blockIdx.x * 64;
  const int lane = tid & 63;
  const int w = tid >> 6;
  const int wm = w >> 1, wn = w & 1;
  const int l16 = lane & 15, lk = lane >> 4;

  const int arow = tid >> 1, aks = (tid & 1) * 32;
  const int br = tid >> 3, bkc = (tid & 7) * 8;

  f32x4 acc[4][2] = {};

  for (int it = 0; it < 4; ++it) {
    const int kb = it * 64;
    __syncthreads();
    {
      const __bf16* ap = &wxT[(size_t)arow * 256 + kb + aks];
      const int wbase = (arow * 64 + aks);
      const int sw = (arow & 7) << 3;
#pragma unroll
      for (int m = 0; m < 4; ++m)
        *(bf16x8*)&sA[(wbase + m * 8) ^ sw] = *(const bf16x8*)(ap + m * 8);
      const float* bp = &emb_w[(size_t)(v0 + br) * 256 + kb + bkc];
      f32x4 x0 = *(const f32x4*)(bp);
      f32x4 x1 = *(const f32x4*)(bp + 4);
      bf16x8 bw;
      bw[0] = (__bf16)x0[0]; bw[1] = (__bf16)x0[1]; bw[2] = (__bf16)x0[2]; bw[3] = (__bf16)x0[3];
      bw[4] = (__bf16)x1[0]; bw[5] = (__bf16)x1[1]; bw[6] = (__bf16)x1[2]; bw[7] = (__bf16)x1[3];
      *(bf16x8*)&sB[(br * 64 + bkc) ^ ((br & 7) << 3)] = bw;
    }
    __syncthreads();
#pragma unroll
    for (int s = 0; s < 2; ++s) {
      bf16x8 af[4], bfr[2];
#pragma unroll
      for (int i = 0; i < 4; ++i) {
        const int r = wm * 64 + i * 16 + l16;
        af[i] = *(const bf16x8*)&sA[(r * 64 + s * 32 + lk * 8) ^ ((r & 7) << 3)];
      }
#pragma unroll
      for (int j = 0; j < 2; ++j) {
        const int c = wn * 32 + j * 16 + l16;
        bfr[j] = *(const bf16x8*)&sB[(c * 64 + s * 32 + lk * 8) ^ ((c & 7) << 3)];
      }
#pragma unroll
      for (int i = 0; i < 4; ++i)
#pragma unroll
        for (int j = 0; j < 2; ++j)
          acc[i][j] = __builtin_amdgcn_mfma_f32_16x16x32_bf16(af[i], bfr[j], acc[i][j], 0, 0, 0);
    }
  }

#pragma unroll
  for (int i = 0; i < 4; ++i)
#pragma unroll
    for (int j = 0; j < 2; ++j)
#pragma unroll
      for (int e = 0; e < 4; ++e) {
        const int h = wm * 64 + i * 16 + lk * 4 + e;
        const int v = v0 + wn * 32 + j * 16 + l16;
        w2t[(size_t)h * 8000 + v] = (__bf16)acc[i][j][e];
      }
}

// ---------------- c2[h] = emb_b @ wx + hb ----------------
__global__ __launch_bounds__(256) void k_c2(const float* __restrict__ emb_b,
                                            const float* __restrict__ wx,
                                            const float* __restrict__ hb,
                                            float* __restrict__ c2) {
  const int h = threadIdx.x;
  float s = hb[h];
#pragma unroll 8
  for (int k = 0; k < 256; ++k) s += emb_b[k] * wx[k * 256 + h];
  c2[h] = s;
}

// ---------------- embedding GEMM: part[kc] = inputs @ W2 ----------------
// BM=32, BN=256, BK=64, KSPLIT=5. grid (128, 5), 512 thr = 8 waves (2M x 4N),
// wave tile 16x64. Double-buffered LDS, 1 barrier/iter, loads issued 2 iters ahead.
__global__ __launch_bounds__(512) void k_embed_gemm2(const float* __restrict__ inp,
                                                     const __bf16* __restrict__ w2t,
                                                     float* __restrict__ part) {
  __shared__ __bf16 sA[2][32 * 64];   // 8 KB
  __shared__ __bf16 sB[2][256 * 64];  // 64 KB
  const int tid = threadIdx.x;
  const int m0 = blockIdx.x * 32;
  const int kc = blockIdx.y;
  const size_t kbase = (size_t)kc * KCH;
  const int lane = tid & 63;
  const int w = tid >> 6;
  const int wm = w >> 2, wn = w & 3;
  const int l16 = lane & 15, lk = lane >> 4;

  const int ar = tid >> 4, ac = (tid & 15) * 4;  // A: 32 rows x 16 thr, 4 f32 each
  const int bc = tid >> 1, bk = (tid & 1) * 32;  // B: 256 cols x 2 thr, 32 bf16 each
  const int aswz = (ar & 7) << 3;
  const int bswz = (bc & 7) << 3;

  const float* aptr = &inp[(size_t)(m0 + ar) * 8000 + kbase + ac];
  const __bf16* bptr = &w2t[(size_t)bc * 8000 + kbase + bk];

  f32x4 acc[4] = {};
  f32x4 a0;
  bf16x8 b0, b1, b2, b3;

  // prologue: it0 -> buf0; preload it1 regs
  a0 = *(const f32x4*)(aptr);
  b0 = *(const bf16x8*)(bptr);
  b1 = *(const bf16x8*)(bptr + 8);
  b2 = *(const bf16x8*)(bptr + 16);
  b3 = *(const bf16x8*)(bptr + 24);
  {
    bf16x4 aw;
    aw[0] = (__bf16)a0[0]; aw[1] = (__bf16)a0[1]; aw[2] = (__bf16)a0[2]; aw[3] = (__bf16)a0[3];
    *(bf16x4*)&sA[0][(ar * 64 + ac) ^ aswz] = aw;
    *(bf16x8*)&sB[0][(bc * 64 + bk + 0) ^ bswz] = b0;
    *(bf16x8*)&sB[0][(bc * 64 + bk + 8) ^ bswz] = b1;
    *(bf16x8*)&sB[0][(bc * 64 + bk + 16) ^ bswz] = b2;
    *(bf16x8*)&sB[0][(bc * 64 + bk + 24) ^ bswz] = b3;
  }
  a0 = *(const f32x4*)(aptr + 64);
  b0 = *(const bf16x8*)(bptr + 64);
  b1 = *(const bf16x8*)(bptr + 72);
  b2 = *(const bf16x8*)(bptr + 80);
  b3 = *(const bf16x8*)(bptr + 88);
  __syncthreads();

  for (int it = 0; it < NITER; ++it) {
    const int cur = it & 1;
    // stage it+1 (regs) into the other buffer
    if (it + 1 < NITER) {
      bf16x4 aw;
      aw[0] = (__bf16)a0[0]; aw[1] = (__bf16)a0[1]; aw[2] = (__bf16)a0[2]; aw[3] = (__bf16)a0[3];
      *(bf16x4*)&sA[cur ^ 1][(ar * 64 + ac) ^ aswz] = aw;
      *(bf16x8*)&sB[cur ^ 1][(bc * 64 + bk + 0) ^ bswz] = b0;
      *(bf16x8*)&sB[cur ^ 1][(bc * 64 + bk + 8) ^ bswz] = b1;
      *(bf16x8*)&sB[cur ^ 1][(bc * 64 + bk + 16) ^ bswz] = b2;
      *(bf16x8*)&sB[cur ^ 1][(bc * 64 + bk + 24) ^ bswz] = b3;
    }
    // issue loads for it+2 (in flight across the barrier)
    if (it + 2 < NITER) {
      const float* ap = aptr + (size_t)(it + 2) * 64;
      const __bf16* bp = bptr + (size_t)(it + 2) * 64;
      a0 = *(const f32x4*)(ap);
      b0 = *(const bf16x8*)(bp);
      b1 = *(const bf16x8*)(bp + 8);
      b2 = *(const bf16x8*)(bp + 16);
      b3 = *(const bf16x8*)(bp + 24);
    }
    // compute from current buffer
#pragma unroll
    for (int s = 0; s < 2; ++s) {
      bf16x8 af, bfb[4];
      {
        const int r = wm * 16 + l16;
        af = *(const bf16x8*)&sA[cur][(r * 64 + s * 32 + lk * 8) ^ ((r & 7) << 3)];
      }
#pragma unroll
      for (int j = 0; j < 4; ++j) {
        const int c = wn * 64 + j * 16 + l16;
        bfb[j] = *(const bf16x8*)&sB[cur][(c * 64 + s * 32 + lk * 8) ^ ((c & 7) << 3)];
      }
#pragma unroll
      for (int j = 0; j < 4; ++j)
        acc[j] = __builtin_amdgcn_mfma_f32_16x16x32_bf16(af, bfb[j], acc[j], 0, 0, 0);
    }
    __syncthreads();
  }

#pragma unroll
  for (int j = 0; j < 4; ++j)
#pragma unroll
    for (int e = 0; e < 4; ++e) {
      const int gr = m0 + wm * 16 + lk * 4 + e;
      const int gc = wn * 64 + j * 16 + l16;
      part[((size_t)kc * 4096 + gr) * 256 + gc] = acc[j][e];
    }
}

// ---------------- reduce partials + c2 -> xw4[b][t][h] ----------------
__global__ __launch_bounds__(256) void k_reduce2(const float* __restrict__ part,
                                                 const float* __restrict__ c2,
                                                 float* __restrict__ xw4) {
  const int m0 = blockIdx.x * 16;
  const int h = threadIdx.x;
  const float cv = c2[h];
#pragma unroll
  for (int mi = 0; mi < 16; ++mi) {
    const int m = m0 + mi;
    float s = cv;
#pragma unroll
    for (int c = 0; c < KSPLIT; ++c) s += part[((size_t)c * 4096 + m) * 256 + h];
    const int b = m >> 9, t = m & 511;
    xw4[((size_t)b * 512 + t) * 256 + h] = s;
  }
}

// ---------------- sequential RNN scan: per-batch, 8 blocks, 256 steps/dispatch ----------------
__global__ __launch_bounds__(256, 1) void k_rnn_scan(const __bf16* __restrict__ whT,
                                                     const float* __restrict__ xw4,
                                                     float* __restrict__ hT,
                                                     int t0) {
  __shared__ __bf16 h2[2][256];
  const int tid = threadIdx.x;
  const int lane = tid & 63;
  const int w = tid >> 6;            // 0..3
  const int l16 = lane & 15, lk = lane >> 4;
  const int b = blockIdx.x;
  const bool act = (l16 == 0);
  const bool oact = (lk == 0);
  const int colb = w * 64 + l16;

  bf16x8 whB[4][8];
#pragma unroll
  for (int j = 0; j < 4; ++j) {
    const int col = colb + j * 16;
#pragma unroll
    for (int s = 0; s < 8; ++s)
      whB[j][s] = *(const bf16x8*)&whT[(size_t)col * 256 + s * 32 + lk * 8];
  }

  h2[0][tid] = (t0 == 0) ? (__bf16)0.0f : (__bf16)hT[b * 256 + tid];

  const float* xwb = &xw4[(size_t)b * 512 * 256];
  float xvA[4], xvB[4], nA[4], nB[4];
#pragma unroll
  for (int j = 0; j < 4; ++j) {
    xvA[j] = xwb[(size_t)(t0 + 0) * 256 + colb + j * 16];
    xvB[j] = xwb[(size_t)(t0 + 1) * 256 + colb + j * 16];
  }

  bf16x8 af[8];
#pragma unroll
  for (int s = 0; s < 8; ++s) af[s] = bf16x8{};

  __syncthreads();

#define RNN_STEP(RD, WR, XV, LAST_T)                                              \
  {                                                                               \
    if (act) {                                                                    \
      _Pragma("unroll") for (int s = 0; s < 8; ++s)                               \
          af[s] = *(const bf16x8*)&h2[RD][s * 32 + lk * 8];                       \
    }                                                                             \
    float hn[4];                                                                  \
    _Pragma("unroll") for (int j = 0; j < 4; ++j) {                               \
      f32x4 pA = {}, pB = {};                                                     \
      pA[0] = oact ? (XV)[j] : 0.0f;                                              \
      pA = __builtin_amdgcn_mfma_f32_16x16x32_bf16(af[0], whB[j][0], pA, 0, 0, 0);\
      pB = __builtin_amdgcn_mfma_f32_16x16x32_bf16(af[1], whB[j][1], pB, 0, 0, 0);\
      pA = __builtin_amdgcn_mfma_f32_16x16x32_bf16(af[2], whB[j][2], pA, 0, 0, 0);\
      pB = __builtin_amdgcn_mfma_f32_16x16x32_bf16(af[3], whB[j][3], pB, 0, 0, 0);\
      pA = __builtin_amdgcn_mfma_f32_16x16x32_bf16(af[4], whB[j][4], pA, 0, 0, 0);\
      pB = __builtin_amdgcn_mfma_f32_16x16x32_bf16(af[5], whB[j][5], pB, 0, 0, 0);\
      pA = __builtin_amdgcn_mfma_f32_16x16x32_bf16(af[6], whB[j][6], pA, 0, 0, 0);\
      pB = __builtin_amdgcn_mfma_f32_16x16x32_bf16(af[7], whB[j][7], pB, 0, 0, 0);\
      const float v = pA[0] + pB[0];                                              \
      const float e2 = __builtin_amdgcn_exp2f(v * 2.8853900817779268f);           \
      hn[j] = __builtin_fmaf(-2.0f, __builtin_amdgcn_rcpf(e2 + 1.0f), 1.0f);      \
    }                                                                             \
    if (oact) {                                                                   \
      _Pragma("unroll") for (int j = 0; j < 4; ++j) {                             \
        h2[WR][colb + j * 16] = (__bf16)hn[j];                                    \
        if (LAST_T) hT[b * 256 + colb + j * 16] = hn[j];                          \
      }                                                                           \
    }                                                                             \
    asm volatile("s_waitcnt lgkmcnt(0)" ::: "memory");                            \
    __builtin_amdgcn_sched_barrier(0);                                            \
    __builtin_amdgcn_s_barrier();                                                 \
    __builtin_amdgcn_sched_barrier(0);                                            \
  }

  for (int tt = 0; tt < 128; ++tt) {
    const int tg = t0 + tt * 2;
    const bool more = (tt < 127);
    if (more) {
#pragma unroll
      for (int j = 0; j < 4; ++j) nA[j] = xwb[(size_t)(tg + 2) * 256 + colb + j * 16];
    }
    RNN_STEP(0, 1, xvA, false)
    if (more) {
#pragma unroll
      for (int j = 0; j < 4; ++j) nB[j] = xwb[(size_t)(tg + 3) * 256 + colb + j * 16];
    }
    RNN_STEP(1, 0, xvB, (tt == 127))
    if (more) {
#pragma unroll
      for (int j = 0; j < 4; ++j) { xvA[j] = nA[j]; xvB[j] = nB[j]; }
    }
  }
#undef RNN_STEP
}

// ---------------- logits: raw logits (+out_b) -> ws, 64 blocks ----------------
__global__ __launch_bounds__(256) void k_logits(const float* __restrict__ hT,
                                                const float* __restrict__ out_w,
                                                const float* __restrict__ out_b,
                                                float* __restrict__ logits) {
  __shared__ float hs[256];
  const int vc = blockIdx.x, b = blockIdx.y;
  const int tid = threadIdx.x;
  hs[tid] = hT[b * 256 + tid];
  __syncthreads();

  const int v0 = vc * 1024 + tid * 4;
  if (v0 >= 8000) return;
  f32x4 acc = *(const f32x4*)&out_b[v0];
#pragma unroll 8
  for (int k = 0; k < 256; ++k) {
    acc += hs[k] * (*(const f32x4*)&out_w[(size_t)k * 8000 + v0]);
  }
  *(f32x4*)&logits[(size_t)b * 8192 + v0] = acc;
}

// ---------------- softmax over precomputed logits, 8 blocks ----------------
__global__ __launch_bounds__(1024) void k_softmax8(const float* __restrict__ logits,
                                                   float* __restrict__ out) {
  __shared__ float red[16];
  const int b = blockIdx.x;
  const int tid = threadIdx.x;
  const bool active = tid < 1000;
  const int v0 = tid * 8;
  f32x4 acc0 = {}, acc1 = {};
  if (active) {
    acc0 = *(const f32x4*)&logits[(size_t)b * 8192 + v0];
    acc1 = *(const f32x4*)&logits[(size_t)b * 8192 + v0 + 4];
  }

  float m = -__builtin_huge_valf();
  if (active) {
#pragma unroll
    for (int e = 0; e < 4; ++e) m = fmaxf(m, fmaxf(acc0[e], acc1[e]));
  }
#pragma unroll
  for (int off = 32; off > 0; off >>= 1) m = fmaxf(m, __shfl_xor(m, off));
  if ((tid & 63) == 0) red[tid >> 6] = m;
  __syncthreads();
  if (tid < 64) {
    float t = (tid < 16) ? red[tid] : -__builtin_huge_valf();
#pragma unroll
    for (int off = 8; off > 0; off >>= 1) t = fmaxf(t, __shfl_xor(t, off));
    if (tid == 0) red[0] = t;
  }
  __syncthreads();
  const float M = red[0];

  f32x4 e0 = {}, e1 = {};
  float s = 0.0f;
  if (active) {
#pragma unroll
    for (int e = 0; e < 4; ++e) {
      e0[e] = __expf(acc0[e] - M);
      e1[e] = __expf(acc1[e] - M);
      s += e0[e] + e1[e];
    }
  }
#pragma unroll
  for (int off = 32; off > 0; off >>= 1) s += __shfl_xor(s, off);
  if ((tid & 63) == 0) red[tid >> 6] = s;
  __syncthreads();
  if (tid < 64) {
    float t = (tid < 16) ? red[tid] : 0.0f;
#pragma unroll
    for (int off = 8; off > 0; off >>= 1) t += __shfl_xor(t, off);
    if (tid == 0) red[0] = t;
  }
  __syncthreads();
  const float inv = 1.0f / red[0];

  if (active) {
    float* op = &out[(size_t)b * 8000 + v0];
    *(f32x4*)(op) = e0 * inv;
    *(f32x4*)(op + 4) = e1 * inv;
  }
}

// ---------------- launch ----------------
extern "C" void kernel_launch(void* const* d_in, const int* in_sizes, int n_in,
                              void* d_out, int out_size, void* d_ws, size_t ws_size,
                              hipStream_t stream) {
  const float* inputs = (const float*)d_in[0];  // (8,512,8000)
  const float* emb_w  = (const float*)d_in[1];  // (8000,256)
  const float* emb_b  = (const float*)d_in[2];  // (256)
  const float* wx     = (const float*)d_in[3];  // (256,256)
  const float* wh     = (const float*)d_in[4];  // (256,256)
  const float* hb     = (const float*)d_in[5];  // (1,256)
  const float* out_w  = (const float*)d_in[6];  // (256,8000)
  const float* out_b  = (const float*)d_in[7];  // (8000)
  float* out = (float*)d_out;                   // (8,1,8000)

  char* ws = (char*)d_ws;
  __bf16* whT   = (__bf16*)(ws + 0);             //   131,072
  __bf16* wxT   = (__bf16*)(ws + 131072);        //   131,072
  __bf16* w2t   = (__bf16*)(ws + 262144);        // 4,096,000  (256 x 8000 bf16)
  float* part   = (float*)(ws + 4358144);        // 20,971,520 (5 x 4096 x 256 f32)
  float* xw4    = (float*)(ws + 25329664);       // 4,194,304  ([8][512][256] f32)
  float* hT     = (float*)(ws + 29523968);       //     8,192
  float* c2     = (float*)(ws + 29532160);       //     1,024
  float* logits = (float*)(ws + 29533184);       //   262,144

  k_transpose_bf16<<<dim3(4, 4), 256, 0, stream>>>(wh, whT, 256, 256);
  k_transpose_bf16<<<dim3(4, 4), 256, 0, stream>>>(wx, wxT, 256, 256);
  k_w2m<<<125, 512, 0, stream>>>(wxT, emb_w, w2t);
  k_c2<<<1, 256, 0, stream>>>(emb_b, wx, hb, c2);
  k_embed_gemm2<<<dim3(128, KSPLIT), 512, 0, stream>>>(inputs, w2t, part);
  k_reduce2<<<256, 256, 0, stream>>>(part, c2, xw4);
  k_rnn_scan<<<8, 256, 0, stream>>>(whT, xw4, hT, 0);
  k_rnn_scan<<<8, 256, 0, stream>>>(whT, xw4, hT, 256);
  k_logits<<<dim3(8, 8), 256, 0, stream>>>(hT, out_w, out_b, logits);
  k_softmax8<<<8, 1024, 0, stream>>>(logits, out);
}